// Round 8
// baseline (335.327 us; speedup 1.0000x reference)
//
#include <hip/hip_runtime.h>
#include <math.h>

#define NB 2048
#define NL 256
#define NH 512

typedef unsigned short ushort_t;
typedef unsigned int uint_t;
typedef short s16x8 __attribute__((ext_vector_type(8)));
typedef short s16x4 __attribute__((ext_vector_type(4)));
typedef float f32x4 __attribute__((ext_vector_type(4)));

__device__ __forceinline__ float wsum(float v){
  #pragma unroll
  for (int o = 32; o; o >>= 1) v += __shfl_xor(v, o);
  return v;
}
__device__ __forceinline__ float wmax(float v){
  #pragma unroll
  for (int o = 32; o; o >>= 1) v = fmaxf(v, __shfl_xor(v, o));
  return v;
}
__device__ __forceinline__ ushort_t f2bf(float f){
  union { float f; unsigned u; } v; v.f = f;
  unsigned r = v.u + 0x7fffu + ((v.u >> 16) & 1u);
  return (ushort_t)(r >> 16);
}
__device__ __forceinline__ float bf2f(unsigned u16){
  union { unsigned u; float f; } v; v.u = u16 << 16;
  return v.f;
}

// ---------------------------------------------------------------------------
// kPrepAll (1237 blocks x 256):
//  bid <  512: hidden fp32 -> bf16 into A2 right half (lda 1024)
//  bid < 1024: WTG[n][k] bf16 gate-interleaved blockdiag GRU weight (2048x1024)
//  bid < 1088: WAB = bf16 copy of attn_W bottom (rows 512..1023, [k][c] kept)
//  bid < 1216: WCB = bf16 copy of comb_W bottom (rows 512..1023, [k][c] kept)
//  bid < 1228: p,q (attn top rank-2) / p2,q2 (comb top rank-2)
//  bid ==1228: stats = {mW, mb, Su2, Suv, Sv2}
//  bid > 1228: out0[b] = out_b[0]  (accumulator init for kGRU atomics)
// ---------------------------------------------------------------------------
__global__ __launch_bounds__(256)
void kPrepAll(const float* __restrict__ hidden,
              const float* __restrict__ eW, const float* __restrict__ eb,
              const float* __restrict__ attn_W, const float* __restrict__ comb_W,
              const float* __restrict__ Wih, const float* __restrict__ Whh,
              const float* __restrict__ out_b,
              ushort_t* __restrict__ A2, ushort_t* __restrict__ WTG,
              ushort_t* __restrict__ WAB, ushort_t* __restrict__ WCB,
              float* __restrict__ stats,
              float* __restrict__ p, float* __restrict__ q,
              float* __restrict__ p2, float* __restrict__ q2,
              float* __restrict__ out0)
{
  const int bid = blockIdx.x, tid = threadIdx.x;
  if (bid < 512) {                       // hidden -> bf16 A2 right half
    const int idx = (bid*256 + tid) * 8;
    const int b = idx >> 9, h = idx & 511;
    float4 v0 = *(const float4*)(hidden + idx);
    float4 v1 = *(const float4*)(hidden + idx + 4);
    s16x8 o;
    o[0]=f2bf(v0.x); o[1]=f2bf(v0.y); o[2]=f2bf(v0.z); o[3]=f2bf(v0.w);
    o[4]=f2bf(v1.x); o[5]=f2bf(v1.y); o[6]=f2bf(v1.z); o[7]=f2bf(v1.w);
    *(s16x8*)&A2[(size_t)b*1024 + 512 + h] = o;
    return;
  }
  if (bid < 1024) {                      // WTG bf16 gate-blockdiag
    const int b2 = bid - 512, bx = b2 & 31, by = b2 >> 5;
    const int n = bx*64 + (tid & 63);
    const int ksub = by*64 + (tid >> 6)*16;
    const int g = n >> 6, t = (n >> 4) & 3, c = (g << 4) | (n & 15);
    const int sc = (t == 0) ? c : (t == 1) ? (512 + c) : (1024 + c);
    ushort_t vals[16];
    #pragma unroll
    for (int kk = 0; kk < 16; ++kk) {
      int k = ksub + kk;
      float v;
      if (k < 512) v = (t == 3) ? 0.f : Wih[(size_t)k*1536 + sc];
      else         v = (t == 2) ? 0.f : Whh[(size_t)(k-512)*1536 + sc];
      vals[kk] = f2bf(v);
    }
    *(s16x8*)&WTG[(size_t)n*1024 + ksub]     = *(s16x8*)&vals[0];
    *(s16x8*)&WTG[(size_t)n*1024 + ksub + 8] = *(s16x8*)&vals[8];
    return;
  }
  if (bid < 1088) {                      // WAB bf16 flat copy (131072 elems)
    const int idx = (bid - 1024)*2048 + tid*8;
    float4 v0 = *(const float4*)(attn_W + 131072 + idx);
    float4 v1 = *(const float4*)(attn_W + 131072 + idx + 4);
    s16x8 o;
    o[0]=f2bf(v0.x); o[1]=f2bf(v0.y); o[2]=f2bf(v0.z); o[3]=f2bf(v0.w);
    o[4]=f2bf(v1.x); o[5]=f2bf(v1.y); o[6]=f2bf(v1.z); o[7]=f2bf(v1.w);
    *(s16x8*)&WAB[idx] = o;
    return;
  }
  if (bid < 1216) {                      // WCB bf16 flat copy (262144 elems)
    const int idx = (bid - 1088)*2048 + tid*8;
    float4 v0 = *(const float4*)(comb_W + 262144 + idx);
    float4 v1 = *(const float4*)(comb_W + 262144 + idx + 4);
    s16x8 o;
    o[0]=f2bf(v0.x); o[1]=f2bf(v0.y); o[2]=f2bf(v0.z); o[3]=f2bf(v0.w);
    o[4]=f2bf(v1.x); o[5]=f2bf(v1.y); o[6]=f2bf(v1.z); o[7]=f2bf(v1.w);
    *(s16x8*)&WCB[idx] = o;
    return;
  }
  if (bid > 1228) {                      // out0 init
    out0[(bid-1229)*256 + tid] = out_b[0];
    return;
  }
  // rank-2 projections + stats
  {
    __shared__ float rw[4], rb[4];
    __shared__ float pa[4][64], pb[4][64];
    const int lane = tid & 63, wv = tid >> 6;
    float swv = eW[tid] + eW[tid + 256];
    float sbv = eb[tid] + eb[tid + 256];
    swv = wsum(swv); sbv = wsum(sbv);
    if (lane == 0) { rw[wv] = swv; rb[wv] = sbv; }
    __syncthreads();
    const float mW = (rw[0]+rw[1]+rw[2]+rw[3]) * (1.f/NH);
    const float mb = (rb[0]+rb[1]+rb[2]+rb[3]) * (1.f/NH);

    if (bid == 1228) {
      float u0 = eW[tid]-mW, u1 = eW[tid+256]-mW;
      float v0 = eb[tid]-mb, v1 = eb[tid+256]-mb;
      float s2 = u0*u0 + u1*u1, s3 = u0*v0 + u1*v1, s4 = v0*v0 + v1*v1;
      s2 = wsum(s2); s3 = wsum(s3); s4 = wsum(s4);
      if (lane == 0) { pa[0][wv] = s2; pa[1][wv] = s3; pa[2][wv] = s4; }
      __syncthreads();
      if (tid == 0) {
        stats[0] = mW; stats[1] = mb;
        stats[2] = pa[0][0]+pa[0][1]+pa[0][2]+pa[0][3];
        stats[3] = pa[1][0]+pa[1][1]+pa[1][2]+pa[1][3];
        stats[4] = pa[2][0]+pa[2][1]+pa[2][2]+pa[2][3];
      }
      return;
    }
    const int bid2 = bid - 1216;
    const float* Wsrc; int ldw, c0; float *op, *oq;
    if (bid2 < 4) { Wsrc = attn_W; ldw = NL; c0 = bid2*64;     op = p  + c0; oq = q  + c0; }
    else          { Wsrc = comb_W; ldw = NH; c0 = (bid2-4)*64; op = p2 + c0; oq = q2 + c0; }
    const int c = c0 + lane;
    const int hc = tid >> 6;
    float ap = 0.f, aq = 0.f;
    #pragma unroll 4
    for (int h = hc*128; h < hc*128 + 128; ++h) {
      float w = Wsrc[(size_t)h*ldw + c];
      ap = fmaf(eW[h]-mW, w, ap);
      aq = fmaf(eb[h]-mb, w, aq);
    }
    pa[hc][lane] = ap; pb[hc][lane] = aq;
    __syncthreads();
    if (hc == 0) {
      op[lane] = pa[0][lane]+pa[1][lane]+pa[2][lane]+pa[3][lane];
      oq[lane] = pb[0][lane]+pb[1][lane]+pb[2][lane]+pb[3][lane];
    }
  }
}

// ---------------------------------------------------------------------------
// kFused (512 blocks x 256 thr): 4 batches per block.
//  A: logits[4][256] = h0 . WAB + attn_b + rank2(e)  (bf16 weights, L2,
//     coalesced along c; h0 broadcast from LDS). 4-batch amortization keeps
//     aggregate weight traffic at 512 x 256KB = 128 MB (round-6 bug was 2048x).
//  softmax: wave w owns batch w (wave-local, no cross-wave reduce).
//  B: a[4][512] = sum_l wl[l]*enc[b,l,:]  (the 1.07 GB HBM stream, fp32 LDS)
//  C: xt[4][512] = relu(a . WCB + comb_b + rank2)  -> bf16 A2 left half.
// ---------------------------------------------------------------------------
__global__ __launch_bounds__(256)
void kFused(const float* __restrict__ x, const float* __restrict__ hidden,
            const float* __restrict__ enc,
            const ushort_t* __restrict__ WAB, const float* __restrict__ attn_b,
            const float* __restrict__ p, const float* __restrict__ q,
            const ushort_t* __restrict__ WCB, const float* __restrict__ comb_b,
            const float* __restrict__ p2, const float* __restrict__ q2,
            const float* __restrict__ stats,
            float* __restrict__ attn_out, ushort_t* __restrict__ A2)
{
  __shared__ __align__(16) float h0s[4][NH];   // 8 KB
  __shared__ __align__(16) float lgt[4][NL];   // 4 KB (logits, then softmax w)
  __shared__ __align__(16) float a_s[4][NH];   // 8 KB
  const int tid = threadIdx.x, lane = tid & 63, wv = tid >> 6;
  const int b0 = blockIdx.x * 4;

  { // load h0 for 4 batches (contiguous 8 KB)
    const float4* hp = (const float4*)(hidden + (size_t)b0*NH);
    ((float4*)h0s)[tid]       = hp[tid];
    ((float4*)h0s)[tid + 256] = hp[tid + 256];
  }
  const float S2 = stats[2], S3 = stats[3], S4 = stats[4];
  float al[4], be[4];
  #pragma unroll
  for (int i = 0; i < 4; ++i) {
    float xv = x[b0 + i];
    float rs = rsqrtf((xv*xv*S2 + 2.f*xv*S3 + S4)*(1.0f/NH) + 1e-5f);
    al[i] = xv * rs; be[i] = rs;
  }
  __syncthreads();

  // --- phase A: logits, thread owns col c=tid for all 4 batches
  {
    float acc0 = 0.f, acc1 = 0.f, acc2 = 0.f, acc3 = 0.f;
    #pragma unroll 4
    for (int k = 0; k < NH; ++k) {
      float w = bf2f(WAB[k*NL + tid]);
      acc0 = fmaf(h0s[0][k], w, acc0);
      acc1 = fmaf(h0s[1][k], w, acc1);
      acc2 = fmaf(h0s[2][k], w, acc2);
      acc3 = fmaf(h0s[3][k], w, acc3);
    }
    const float ab = attn_b[tid], pc = p[tid], qc = q[tid];
    lgt[0][tid] = acc0 + ab + al[0]*pc + be[0]*qc;
    lgt[1][tid] = acc1 + ab + al[1]*pc + be[1]*qc;
    lgt[2][tid] = acc2 + ab + al[2]*pc + be[2]*qc;
    lgt[3][tid] = acc3 + ab + al[3]*pc + be[3]*qc;
  }
  __syncthreads();

  // --- softmax: wave wv owns batch wv (4 vals per lane over L=256)
  {
    float v0 = lgt[wv][lane],       v1 = lgt[wv][lane + 64];
    float v2 = lgt[wv][lane + 128], v3 = lgt[wv][lane + 192];
    float m = wmax(fmaxf(fmaxf(v0, v1), fmaxf(v2, v3)));
    v0 = expf(v0 - m); v1 = expf(v1 - m); v2 = expf(v2 - m); v3 = expf(v3 - m);
    float inv = 1.f / wsum(v0 + v1 + v2 + v3);
    v0 *= inv; v1 *= inv; v2 *= inv; v3 *= inv;
    lgt[wv][lane]       = v0; lgt[wv][lane + 64]  = v1;
    lgt[wv][lane + 128] = v2; lgt[wv][lane + 192] = v3;
    size_t base = (size_t)(b0 + wv)*NL;
    attn_out[base + lane]       = v0;
    attn_out[base + lane + 64]  = v1;
    attn_out[base + lane + 128] = v2;
    attn_out[base + lane + 192] = v3;
  }
  __syncthreads();

  // --- phase B: stream enc (HBM-bound). col/half split, LDS combine.
  {
    const int col = tid & 127, half = tid >> 7;
    #pragma unroll
    for (int bi = 0; bi < 4; ++bi) {
      const float4* ep = (const float4*)(enc + (size_t)(b0 + bi)*NL*NH);
      float4 acc = {0.f,0.f,0.f,0.f};
      #pragma unroll 8
      for (int l = half*128; l < half*128 + 128; ++l) {
        float w = lgt[bi][l];
        float4 ev = ep[l*(NH/4) + col];
        acc.x = fmaf(w,ev.x,acc.x); acc.y = fmaf(w,ev.y,acc.y);
        acc.z = fmaf(w,ev.z,acc.z); acc.w = fmaf(w,ev.w,acc.w);
      }
      if (half == 0) *(float4*)&a_s[bi][col*4] = acc;
      __syncthreads();
      if (half == 1) {
        float4 o = *(float4*)&a_s[bi][col*4];
        o.x += acc.x; o.y += acc.y; o.z += acc.z; o.w += acc.w;
        *(float4*)&a_s[bi][col*4] = o;
      }
    }
  }
  __syncthreads();

  // --- phase C: xt = relu(a . WCB + comb_b + rank2) -> bf16 A2 left.
  // Thread owns 2 adjacent cols (c0=2*tid) for all 4 batches.
  {
    const int c0 = tid * 2;
    float a00=0.f,a01=0.f,a10=0.f,a11=0.f,a20=0.f,a21=0.f,a30=0.f,a31=0.f;
    #pragma unroll 4
    for (int k = 0; k < NH; ++k) {
      uint_t wpk = *(const uint_t*)&WCB[k*NH + c0];
      float w0 = bf2f(wpk & 0xffffu), w1 = bf2f(wpk >> 16);
      float av0 = a_s[0][k], av1 = a_s[1][k], av2 = a_s[2][k], av3 = a_s[3][k];
      a00 = fmaf(av0,w0,a00); a01 = fmaf(av0,w1,a01);
      a10 = fmaf(av1,w0,a10); a11 = fmaf(av1,w1,a11);
      a20 = fmaf(av2,w0,a20); a21 = fmaf(av2,w1,a21);
      a30 = fmaf(av3,w0,a30); a31 = fmaf(av3,w1,a31);
    }
    float2 cb = *(const float2*)&comb_b[c0];
    float2 pc = *(const float2*)&p2[c0];
    float2 qc = *(const float2*)&q2[c0];
    #pragma unroll
    for (int bi = 0; bi < 4; ++bi) {
      float v0, v1;
      if (bi == 0) { v0 = a00; v1 = a01; }
      else if (bi == 1) { v0 = a10; v1 = a11; }
      else if (bi == 2) { v0 = a20; v1 = a21; }
      else { v0 = a30; v1 = a31; }
      v0 = fmaxf(v0 + cb.x + al[bi]*pc.x + be[bi]*qc.x, 0.f);
      v1 = fmaxf(v1 + cb.y + al[bi]*pc.y + be[bi]*qc.y, 0.f);
      uint_t o = (uint_t)f2bf(v0) | ((uint_t)f2bf(v1) << 16);
      *(uint_t*)&A2[(size_t)(b0 + bi)*1024 + c0] = o;
    }
  }
}

// ---------------------------------------------------------------------------
// kGRU: 128x64 tile, 4 waves (4x1). A = [xt|h0] bf16 (lda 1024),
// Bt = WTG (2048x1024). Epilogue: GRU gates -> h_new fp32 + fused out0
// atomic reduce (out0 pre-init to out_b by kPrepAll each launch).
// ---------------------------------------------------------------------------
__global__ __launch_bounds__(256)
void kGRU(const ushort_t* __restrict__ A, const ushort_t* __restrict__ Bt,
          const float* __restrict__ bih, const float* __restrict__ bhh,
          const float* __restrict__ hidden, const float* __restrict__ out_W,
          float* __restrict__ h_out, float* __restrict__ out0)
{
  __shared__ ushort_t As[128][72];
  __shared__ ushort_t Bs[64][72];
  const int tid = threadIdx.x, lane = tid & 63, wr = tid >> 6;
  const int m0 = blockIdx.x * 128, n0 = blockIdx.y * 64;
  const int K = 1024;

  f32x4 acc[2][4];
  #pragma unroll
  for (int i = 0; i < 2; ++i)
    #pragma unroll
    for (int j = 0; j < 4; ++j)
      acc[i][j] = (f32x4){0.f,0.f,0.f,0.f};

  const int srow = tid >> 3, scol = (tid & 7) * 8;
  for (int kt = 0; kt < K; kt += 64) {
    __syncthreads();
    #pragma unroll
    for (int it = 0; it < 4; ++it) {
      const int r = srow + it*32;
      *(s16x8*)&As[r][scol] = *(const s16x8*)&A[(size_t)(m0+r)*1024 + kt + scol];
    }
    #pragma unroll
    for (int it = 0; it < 2; ++it) {
      const int r = srow + it*32;
      *(s16x8*)&Bs[r][scol] = *(const s16x8*)&Bt[(size_t)(n0+r)*K + kt + scol];
    }
    __syncthreads();
    #pragma unroll
    for (int ks = 0; ks < 2; ++ks) {
      const int ko = ks*32 + (lane >> 4)*8;
      s16x8 af[2], bfr[4];
      #pragma unroll
      for (int i = 0; i < 2; ++i) af[i]  = *(const s16x8*)&As[wr*32 + i*16 + (lane & 15)][ko];
      #pragma unroll
      for (int j = 0; j < 4; ++j) bfr[j] = *(const s16x8*)&Bs[j*16 + (lane & 15)][ko];
      #pragma unroll
      for (int i = 0; i < 2; ++i)
        #pragma unroll
        for (int j = 0; j < 4; ++j)
          acc[i][j] = __builtin_amdgcn_mfma_f32_16x16x32_bf16(af[i], bfr[j], acc[i][j], 0, 0, 0);
    }
  }

  const int g = n0 >> 6;
  const int hcol = (g << 4) | (lane & 15);
  const float b_r = bih[hcol]        + bhh[hcol];
  const float b_z = bih[512 + hcol]  + bhh[512 + hcol];
  const float b_i = bih[1024 + hcol];
  const float b_h = bhh[1024 + hcol];
  const float ow  = out_W[hcol];
  #pragma unroll
  for (int i = 0; i < 2; ++i) {
    #pragma unroll
    for (int reg = 0; reg < 4; ++reg) {
      const int row = m0 + wr*32 + i*16 + ((lane >> 4) << 2) + reg;
      float rv = 1.f / (1.f + expf(-(acc[i][0][reg] + b_r)));
      float zv = 1.f / (1.f + expf(-(acc[i][1][reg] + b_z)));
      float nv = tanhf(acc[i][2][reg] + b_i + rv * (acc[i][3][reg] + b_h));
      float h0v = hidden[(size_t)row*NH + hcol];
      float hn = nv + zv * (h0v - nv);
      h_out[(size_t)row*NH + hcol] = hn;
      float partial = hn * ow;
      #pragma unroll
      for (int o = 1; o < 16; o <<= 1) partial += __shfl_xor(partial, o);
      if ((lane & 15) == 0) atomicAdd(&out0[row], partial);
    }
  }
}

// ---------------------------------------------------------------------------
extern "C" void kernel_launch(void* const* d_in, const int* in_sizes, int n_in,
                              void* d_out, int out_size, void* d_ws, size_t ws_size,
                              hipStream_t stream)
{
  const float* x      = (const float*)d_in[0];
  const float* hidden = (const float*)d_in[1];
  const float* enc    = (const float*)d_in[2];
  const float* emb_W  = (const float*)d_in[3];
  const float* emb_b  = (const float*)d_in[4];
  const float* attn_W = (const float*)d_in[5];
  const float* attn_b = (const float*)d_in[6];
  const float* comb_W = (const float*)d_in[7];
  const float* comb_b = (const float*)d_in[8];
  const float* Wih    = (const float*)d_in[9];
  const float* Whh    = (const float*)d_in[10];
  const float* bih    = (const float*)d_in[11];
  const float* bhh    = (const float*)d_in[12];
  const float* out_W  = (const float*)d_in[13];
  const float* out_b  = (const float*)d_in[14];

  float* out      = (float*)d_out;
  float* out0     = out;                          // 2048
  float* out_h    = out + NB;                     // B*H
  float* out_attn = out + NB + (size_t)NB*NH;     // B*L

  float* wsf   = (float*)d_ws;
  float* stats = wsf;              // 16
  float* p     = wsf + 16;         // 256
  float* q     = wsf + 272;        // 256
  float* p2    = wsf + 528;        // 512
  float* q2    = wsf + 1040;       // 512
  ushort_t* usb = (ushort_t*)(wsf + 2048);
  ushort_t* A2  = usb;             // [2048][1024] bf16: [xt | h0]
  ushort_t* WTG = usb + 2097152;   // [2048][1024] bf16
  ushort_t* WAB = usb + 4194304;   // [512][256]   bf16 attn_W bottom
  ushort_t* WCB = usb + 4325376;   // [512][512]   bf16 comb_W bottom

  kPrepAll<<<1237, 256, 0, stream>>>(hidden, emb_W, emb_b, attn_W, comb_W,
                                     Wih, Whh, out_b, A2, WTG, WAB, WCB,
                                     stats, p, q, p2, q2, out0);
  kFused<<<512, 256, 0, stream>>>(x, hidden, enc, WAB, attn_b, p, q,
                                  WCB, comb_b, p2, q2, stats, out_attn, A2);
  kGRU<<<dim3(16, 32), 256, 0, stream>>>(A2, WTG, bih, bhh, hidden, out_W,
                                         out_h, out0);
}

// Round 9
// 281.055 us; speedup vs baseline: 1.1931x; 1.1931x over previous
//
#include <hip/hip_runtime.h>
#include <math.h>

#define NB 2048
#define NL 256
#define NH 512

typedef unsigned short ushort_t;
typedef unsigned int uint_t;
typedef short s16x8 __attribute__((ext_vector_type(8)));
typedef short s16x4 __attribute__((ext_vector_type(4)));
typedef float f32x4 __attribute__((ext_vector_type(4)));

__device__ __forceinline__ float wsum(float v){
  #pragma unroll
  for (int o = 32; o; o >>= 1) v += __shfl_xor(v, o);
  return v;
}
__device__ __forceinline__ float wmax(float v){
  #pragma unroll
  for (int o = 32; o; o >>= 1) v = fmaxf(v, __shfl_xor(v, o));
  return v;
}
__device__ __forceinline__ ushort_t f2bf(float f){
  union { float f; unsigned u; } v; v.f = f;
  unsigned r = v.u + 0x7fffu + ((v.u >> 16) & 1u);
  return (ushort_t)(r >> 16);
}

// ---------------------------------------------------------------------------
// kTiny (53 blocks x 256): pre-stream minimal prep.
//  bid <  32: WTA[c][k] = bf16 attn_W_bottom^T  (256x512)
//  bid <  44: p,q (attn top rank-2, 4 blk) / p2,q2 (comb top rank-2, 8 blk)
//  bid == 44: stats = {mW, mb, Su2, Suv, Sv2}
//  bid >  44: out0[b] = out_b[0] (8 blk)
// ---------------------------------------------------------------------------
__global__ __launch_bounds__(256)
void kTiny(const float* __restrict__ eW, const float* __restrict__ eb,
           const float* __restrict__ attn_W, const float* __restrict__ comb_W,
           const float* __restrict__ out_b,
           ushort_t* __restrict__ WTA, float* __restrict__ stats,
           float* __restrict__ p, float* __restrict__ q,
           float* __restrict__ p2, float* __restrict__ q2,
           float* __restrict__ out0)
{
  const int bid = blockIdx.x, tid = threadIdx.x;
  if (bid < 32) {                        // WTA bf16 transpose
    const int bx = bid & 3, by = bid >> 2;
    const int c = bx*64 + (tid & 63);
    const int ksub = by*64 + (tid >> 6)*16;
    ushort_t vals[16];
    #pragma unroll
    for (int kk = 0; kk < 16; ++kk)
      vals[kk] = f2bf(attn_W[(size_t)(512 + ksub + kk)*NL + c]);
    *(s16x8*)&WTA[(size_t)c*512 + ksub]     = *(s16x8*)&vals[0];
    *(s16x8*)&WTA[(size_t)c*512 + ksub + 8] = *(s16x8*)&vals[8];
    return;
  }
  if (bid > 44) {                        // out0 init
    out0[(bid-45)*256 + tid] = out_b[0];
    return;
  }
  // rank-2 projections + stats
  {
    __shared__ float rw[4], rb[4];
    __shared__ float pa[4][64], pb[4][64];
    const int lane = tid & 63, wv = tid >> 6;
    float swv = eW[tid] + eW[tid + 256];
    float sbv = eb[tid] + eb[tid + 256];
    swv = wsum(swv); sbv = wsum(sbv);
    if (lane == 0) { rw[wv] = swv; rb[wv] = sbv; }
    __syncthreads();
    const float mW = (rw[0]+rw[1]+rw[2]+rw[3]) * (1.f/NH);
    const float mb = (rb[0]+rb[1]+rb[2]+rb[3]) * (1.f/NH);

    if (bid == 44) {
      float u0 = eW[tid]-mW, u1 = eW[tid+256]-mW;
      float v0 = eb[tid]-mb, v1 = eb[tid+256]-mb;
      float s2 = u0*u0 + u1*u1, s3 = u0*v0 + u1*v1, s4 = v0*v0 + v1*v1;
      s2 = wsum(s2); s3 = wsum(s3); s4 = wsum(s4);
      if (lane == 0) { pa[0][wv] = s2; pa[1][wv] = s3; pa[2][wv] = s4; }
      __syncthreads();
      if (tid == 0) {
        stats[0] = mW; stats[1] = mb;
        stats[2] = pa[0][0]+pa[0][1]+pa[0][2]+pa[0][3];
        stats[3] = pa[1][0]+pa[1][1]+pa[1][2]+pa[1][3];
        stats[4] = pa[2][0]+pa[2][1]+pa[2][2]+pa[2][3];
      }
      return;
    }
    const int bid2 = bid - 32;
    const float* Wsrc; int ldw, c0; float *op, *oq;
    if (bid2 < 4) { Wsrc = attn_W; ldw = NL; c0 = bid2*64;     op = p  + c0; oq = q  + c0; }
    else          { Wsrc = comb_W; ldw = NH; c0 = (bid2-4)*64; op = p2 + c0; oq = q2 + c0; }
    const int c = c0 + lane;
    const int hc = tid >> 6;
    float ap = 0.f, aq = 0.f;
    #pragma unroll 4
    for (int h = hc*128; h < hc*128 + 128; ++h) {
      float w = Wsrc[(size_t)h*ldw + c];
      ap = fmaf(eW[h]-mW, w, ap);
      aq = fmaf(eb[h]-mb, w, aq);
    }
    pa[hc][lane] = ap; pb[hc][lane] = aq;
    __syncthreads();
    if (hc == 0) {
      op[lane] = pa[0][lane]+pa[1][lane]+pa[2][lane]+pa[3][lane];
      oq[lane] = pb[0][lane]+pb[1][lane]+pb[2][lane]+pb[3][lane];
    }
  }
}

// ---------------------------------------------------------------------------
// kLogits: 128x64 tile MFMA GEMM, A staged DIRECTLY from fp32 hidden
// (cvt during staging -> no dependency on A2 prep). B = WTA bf16.
// Epilogue: logits = acc + attn_b + rank2 -> fp32 [2048][256]. grid(16,4).
// ---------------------------------------------------------------------------
__global__ __launch_bounds__(256)
void kLogits(const float* __restrict__ hidden, const ushort_t* __restrict__ WTA,
             const float* __restrict__ x, const float* __restrict__ stats,
             const float* __restrict__ p, const float* __restrict__ q,
             const float* __restrict__ attn_b, float* __restrict__ logits)
{
  __shared__ ushort_t As[128][72];
  __shared__ ushort_t Bs[64][72];
  const int tid = threadIdx.x, lane = tid & 63, wr = tid >> 6;
  const int m0 = blockIdx.x * 128, n0 = blockIdx.y * 64;

  f32x4 acc[2][4];
  #pragma unroll
  for (int i = 0; i < 2; ++i)
    #pragma unroll
    for (int j = 0; j < 4; ++j)
      acc[i][j] = (f32x4){0.f,0.f,0.f,0.f};

  const int srow = tid >> 3, scol = (tid & 7) * 8;
  for (int kt = 0; kt < 512; kt += 64) {
    __syncthreads();
    #pragma unroll
    for (int it = 0; it < 4; ++it) {
      const int r = srow + it*32;
      const float* hp = hidden + (size_t)(m0+r)*NH + kt + scol;
      float4 v0 = *(const float4*)hp;
      float4 v1 = *(const float4*)(hp + 4);
      s16x8 o;
      o[0]=f2bf(v0.x); o[1]=f2bf(v0.y); o[2]=f2bf(v0.z); o[3]=f2bf(v0.w);
      o[4]=f2bf(v1.x); o[5]=f2bf(v1.y); o[6]=f2bf(v1.z); o[7]=f2bf(v1.w);
      *(s16x8*)&As[r][scol] = o;
    }
    #pragma unroll
    for (int it = 0; it < 2; ++it) {
      const int r = srow + it*32;
      *(s16x8*)&Bs[r][scol] = *(const s16x8*)&WTA[(size_t)(n0+r)*512 + kt + scol];
    }
    __syncthreads();
    #pragma unroll
    for (int ks = 0; ks < 2; ++ks) {
      const int ko = ks*32 + (lane >> 4)*8;
      s16x8 af[2], bfr[4];
      #pragma unroll
      for (int i = 0; i < 2; ++i) af[i]  = *(const s16x8*)&As[wr*32 + i*16 + (lane & 15)][ko];
      #pragma unroll
      for (int j = 0; j < 4; ++j) bfr[j] = *(const s16x8*)&Bs[j*16 + (lane & 15)][ko];
      #pragma unroll
      for (int i = 0; i < 2; ++i)
        #pragma unroll
        for (int j = 0; j < 4; ++j)
          acc[i][j] = __builtin_amdgcn_mfma_f32_16x16x32_bf16(af[i], bfr[j], acc[i][j], 0, 0, 0);
    }
  }

  const float S2 = stats[2], S3 = stats[3], S4 = stats[4];
  #pragma unroll
  for (int i = 0; i < 2; ++i) {
    #pragma unroll
    for (int reg = 0; reg < 4; ++reg) {
      const int row = m0 + wr*32 + i*16 + ((lane >> 4) << 2) + reg;
      const float xv = x[row];
      const float rs = rsqrtf((xv*xv*S2 + 2.f*xv*S3 + S4)*(1.0f/NH) + 1e-5f);
      const float al = xv*rs, be = rs;
      #pragma unroll
      for (int j = 0; j < 4; ++j) {
        const int col = n0 + j*16 + (lane & 15);
        logits[(size_t)row*NL + col] = acc[i][j][reg] + attn_b[col] + al*p[col] + be*q[col];
      }
    }
  }
}

// ---------------------------------------------------------------------------
// kStreamMega (3136 blocks x 256): prep blocks FIRST so they interleave under
// the stream's HBM phase; stream blocks (the 1.07 GB enc read) dominate.
//  bid <  512: hidden fp32 -> bf16 into A2 right half (lda 1024)
//  bid < 1024: WTG[n][k] bf16 gate-interleaved blockdiag GRU weight (2048x1024)
//  bid < 1088: WTC[c][k] = bf16 comb_W_bottom^T (512x512)
//  else (b = bid-1088): softmax(logits[b]) -> attn_out + wl; then
//       a[512] = sum_l wl[l]*enc[b,l,:] -> bf16 ABF.
// ---------------------------------------------------------------------------
__global__ __launch_bounds__(256)
void kStreamMega(const float* __restrict__ hidden,
                 const float* __restrict__ Wih, const float* __restrict__ Whh,
                 const float* __restrict__ comb_W,
                 const float* __restrict__ logits, const float* __restrict__ enc,
                 ushort_t* __restrict__ A2, ushort_t* __restrict__ WTG,
                 ushort_t* __restrict__ WTC,
                 float* __restrict__ attn_out, ushort_t* __restrict__ ABF)
{
  const int bid = blockIdx.x, tid = threadIdx.x;
  if (bid < 512) {                       // hidden -> bf16 A2 right half
    const int idx = (bid*256 + tid) * 8;
    const int b = idx >> 9, h = idx & 511;
    float4 v0 = *(const float4*)(hidden + idx);
    float4 v1 = *(const float4*)(hidden + idx + 4);
    s16x8 o;
    o[0]=f2bf(v0.x); o[1]=f2bf(v0.y); o[2]=f2bf(v0.z); o[3]=f2bf(v0.w);
    o[4]=f2bf(v1.x); o[5]=f2bf(v1.y); o[6]=f2bf(v1.z); o[7]=f2bf(v1.w);
    *(s16x8*)&A2[(size_t)b*1024 + 512 + h] = o;
    return;
  }
  if (bid < 1024) {                      // WTG bf16 gate-blockdiag
    const int b2 = bid - 512, bx = b2 & 31, by = b2 >> 5;
    const int n = bx*64 + (tid & 63);
    const int ksub = by*64 + (tid >> 6)*16;
    const int g = n >> 6, t = (n >> 4) & 3, c = (g << 4) | (n & 15);
    const int sc = (t == 0) ? c : (t == 1) ? (512 + c) : (1024 + c);
    ushort_t vals[16];
    #pragma unroll
    for (int kk = 0; kk < 16; ++kk) {
      int k = ksub + kk;
      float v;
      if (k < 512) v = (t == 3) ? 0.f : Wih[(size_t)k*1536 + sc];
      else         v = (t == 2) ? 0.f : Whh[(size_t)(k-512)*1536 + sc];
      vals[kk] = f2bf(v);
    }
    *(s16x8*)&WTG[(size_t)n*1024 + ksub]     = *(s16x8*)&vals[0];
    *(s16x8*)&WTG[(size_t)n*1024 + ksub + 8] = *(s16x8*)&vals[8];
    return;
  }
  if (bid < 1088) {                      // WTC bf16 transpose
    const int b2 = bid - 1024, bx = b2 & 7, by = b2 >> 3;
    const int c = bx*64 + (tid & 63);
    const int ksub = by*64 + (tid >> 6)*16;
    ushort_t vals[16];
    #pragma unroll
    for (int kk = 0; kk < 16; ++kk)
      vals[kk] = f2bf(comb_W[(size_t)(512 + ksub + kk)*NH + c]);
    *(s16x8*)&WTC[(size_t)c*512 + ksub]     = *(s16x8*)&vals[0];
    *(s16x8*)&WTC[(size_t)c*512 + ksub + 8] = *(s16x8*)&vals[8];
    return;
  }
  // ---- stream block
  {
    __shared__ float wl[NL];
    __shared__ __align__(16) float4 ps[128];
    __shared__ float sred[4];
    const int lane = tid & 63, wv = tid >> 6;
    const int b = bid - 1088;

    float lg = logits[(size_t)b*NL + tid];
    float m = wmax(lg);
    if (lane == 0) sred[wv] = m;
    __syncthreads();
    m = fmaxf(fmaxf(sred[0], sred[1]), fmaxf(sred[2], sred[3]));
    float e = expf(lg - m);
    float s = wsum(e);
    __syncthreads();
    if (lane == 0) sred[wv] = s;
    __syncthreads();
    const float inv = 1.f / (sred[0] + sred[1] + sred[2] + sred[3]);
    e *= inv;
    wl[tid] = e;
    attn_out[(size_t)b*NL + tid] = e;
    __syncthreads();

    const int col = tid & 127, half = tid >> 7;
    const float4* ep = (const float4*)(enc + (size_t)b*NL*NH);
    float4 acc = {0.f,0.f,0.f,0.f};
    #pragma unroll 4
    for (int l = half*128; l < half*128 + 128; ++l) {
      float w = wl[l];
      float4 ev = ep[l*(NH/4) + col];
      acc.x = fmaf(w,ev.x,acc.x); acc.y = fmaf(w,ev.y,acc.y);
      acc.z = fmaf(w,ev.z,acc.z); acc.w = fmaf(w,ev.w,acc.w);
    }
    if (half == 0) ps[col] = acc;
    __syncthreads();
    if (half == 1) {
      float4 o = ps[col];
      o.x += acc.x; o.y += acc.y; o.z += acc.z; o.w += acc.w;
      s16x4 ov; ov[0]=f2bf(o.x); ov[1]=f2bf(o.y); ov[2]=f2bf(o.z); ov[3]=f2bf(o.w);
      *(s16x4*)&ABF[(size_t)b*NH + col*4] = ov;
    }
  }
}

// ---------------------------------------------------------------------------
// kComb: 128x64 tile. xt = relu(ABF @ WTC^T + comb_b + rank2) -> bf16 A2 left
// (ld 1024). grid(16,8).
// ---------------------------------------------------------------------------
__global__ __launch_bounds__(256)
void kComb(const ushort_t* __restrict__ ABF, const ushort_t* __restrict__ WTC,
           const float* __restrict__ x, const float* __restrict__ stats,
           const float* __restrict__ p2, const float* __restrict__ q2,
           const float* __restrict__ comb_b, ushort_t* __restrict__ A2)
{
  __shared__ ushort_t As[128][72];
  __shared__ ushort_t Bs[64][72];
  const int tid = threadIdx.x, lane = tid & 63, wr = tid >> 6;
  const int m0 = blockIdx.x * 128, n0 = blockIdx.y * 64;

  f32x4 acc[2][4];
  #pragma unroll
  for (int i = 0; i < 2; ++i)
    #pragma unroll
    for (int j = 0; j < 4; ++j)
      acc[i][j] = (f32x4){0.f,0.f,0.f,0.f};

  const int srow = tid >> 3, scol = (tid & 7) * 8;
  for (int kt = 0; kt < 512; kt += 64) {
    __syncthreads();
    #pragma unroll
    for (int it = 0; it < 4; ++it) {
      const int r = srow + it*32;
      *(s16x8*)&As[r][scol] = *(const s16x8*)&ABF[(size_t)(m0+r)*512 + kt + scol];
    }
    #pragma unroll
    for (int it = 0; it < 2; ++it) {
      const int r = srow + it*32;
      *(s16x8*)&Bs[r][scol] = *(const s16x8*)&WTC[(size_t)(n0+r)*512 + kt + scol];
    }
    __syncthreads();
    #pragma unroll
    for (int ks = 0; ks < 2; ++ks) {
      const int ko = ks*32 + (lane >> 4)*8;
      s16x8 af[2], bfr[4];
      #pragma unroll
      for (int i = 0; i < 2; ++i) af[i]  = *(const s16x8*)&As[wr*32 + i*16 + (lane & 15)][ko];
      #pragma unroll
      for (int j = 0; j < 4; ++j) bfr[j] = *(const s16x8*)&Bs[j*16 + (lane & 15)][ko];
      #pragma unroll
      for (int i = 0; i < 2; ++i)
        #pragma unroll
        for (int j = 0; j < 4; ++j)
          acc[i][j] = __builtin_amdgcn_mfma_f32_16x16x32_bf16(af[i], bfr[j], acc[i][j], 0, 0, 0);
    }
  }

  const float S2 = stats[2], S3 = stats[3], S4 = stats[4];
  #pragma unroll
  for (int i = 0; i < 2; ++i) {
    #pragma unroll
    for (int reg = 0; reg < 4; ++reg) {
      const int row = m0 + wr*32 + i*16 + ((lane >> 4) << 2) + reg;
      const float xv = x[row];
      const float rs = rsqrtf((xv*xv*S2 + 2.f*xv*S3 + S4)*(1.0f/NH) + 1e-5f);
      const float al = xv*rs, be = rs;
      #pragma unroll
      for (int j = 0; j < 4; ++j) {
        const int col = n0 + j*16 + (lane & 15);
        float v = acc[i][j][reg] + comb_b[col] + al*p2[col] + be*q2[col];
        A2[(size_t)row*1024 + col] = f2bf(fmaxf(v, 0.f));
      }
    }
  }
}

// ---------------------------------------------------------------------------
// kGRU: 128x128 tile, 4 waves (2x2), wave = 64x64 (4x4 frags). A = [xt|h0]
// bf16 (lda 1024), Bt = WTG (2048x1024). Per wave the 4 j-frags are the 4
// gates (t=j) of column group g=(n0>>6)+wc. Epilogue: gates -> h_new fp32 +
// fused out0 atomic reduce (out0 pre-init to out_b by kTiny). grid(16,16).
// ---------------------------------------------------------------------------
__global__ __launch_bounds__(256)
void kGRU(const ushort_t* __restrict__ A, const ushort_t* __restrict__ Bt,
          const float* __restrict__ bih, const float* __restrict__ bhh,
          const float* __restrict__ hidden, const float* __restrict__ out_W,
          float* __restrict__ h_out, float* __restrict__ out0)
{
  __shared__ ushort_t As[128][72];
  __shared__ ushort_t Bs[128][72];
  const int tid = threadIdx.x, lane = tid & 63, wv = tid >> 6;
  const int wr = wv >> 1, wc = wv & 1;
  const int m0 = blockIdx.x * 128, n0 = blockIdx.y * 128;

  f32x4 acc[4][4];
  #pragma unroll
  for (int i = 0; i < 4; ++i)
    #pragma unroll
    for (int j = 0; j < 4; ++j)
      acc[i][j] = (f32x4){0.f,0.f,0.f,0.f};

  const int srow = tid >> 3, scol = (tid & 7) * 8;
  for (int kt = 0; kt < 1024; kt += 64) {
    __syncthreads();
    #pragma unroll
    for (int it = 0; it < 4; ++it) {
      const int r = srow + it*32;
      *(s16x8*)&As[r][scol] = *(const s16x8*)&A [(size_t)(m0+r)*1024 + kt + scol];
      *(s16x8*)&Bs[r][scol] = *(const s16x8*)&Bt[(size_t)(n0+r)*1024 + kt + scol];
    }
    __syncthreads();
    #pragma unroll
    for (int ks = 0; ks < 2; ++ks) {
      const int ko = ks*32 + (lane >> 4)*8;
      s16x8 af[4], bfr[4];
      #pragma unroll
      for (int f = 0; f < 4; ++f) {
        af[f]  = *(const s16x8*)&As[wr*64 + f*16 + (lane & 15)][ko];
        bfr[f] = *(const s16x8*)&Bs[wc*64 + f*16 + (lane & 15)][ko];
      }
      #pragma unroll
      for (int i = 0; i < 4; ++i)
        #pragma unroll
        for (int j = 0; j < 4; ++j)
          acc[i][j] = __builtin_amdgcn_mfma_f32_16x16x32_bf16(af[i], bfr[j], acc[i][j], 0, 0, 0);
    }
  }

  const int g = (n0 >> 6) + wc;
  const int hcol = (g << 4) | (lane & 15);
  const float b_r = bih[hcol]        + bhh[hcol];
  const float b_z = bih[512 + hcol]  + bhh[512 + hcol];
  const float b_i = bih[1024 + hcol];
  const float b_h = bhh[1024 + hcol];
  const float ow  = out_W[hcol];
  #pragma unroll
  for (int i = 0; i < 4; ++i) {
    #pragma unroll
    for (int reg = 0; reg < 4; ++reg) {
      const int row = m0 + wr*64 + i*16 + ((lane >> 4) << 2) + reg;
      float rv = 1.f / (1.f + expf(-(acc[i][0][reg] + b_r)));
      float zv = 1.f / (1.f + expf(-(acc[i][1][reg] + b_z)));
      float nv = tanhf(acc[i][2][reg] + b_i + rv * (acc[i][3][reg] + b_h));
      float h0v = hidden[(size_t)row*NH + hcol];
      float hn = nv + zv * (h0v - nv);
      h_out[(size_t)row*NH + hcol] = hn;
      float partial = hn * ow;
      #pragma unroll
      for (int o = 1; o < 16; o <<= 1) partial += __shfl_xor(partial, o);
      if ((lane & 15) == 0) atomicAdd(&out0[row], partial);
    }
  }
}

// ---------------------------------------------------------------------------
extern "C" void kernel_launch(void* const* d_in, const int* in_sizes, int n_in,
                              void* d_out, int out_size, void* d_ws, size_t ws_size,
                              hipStream_t stream)
{
  const float* x      = (const float*)d_in[0];
  const float* hidden = (const float*)d_in[1];
  const float* enc    = (const float*)d_in[2];
  const float* emb_W  = (const float*)d_in[3];
  const float* emb_b  = (const float*)d_in[4];
  const float* attn_W = (const float*)d_in[5];
  const float* attn_b = (const float*)d_in[6];
  const float* comb_W = (const float*)d_in[7];
  const float* comb_b = (const float*)d_in[8];
  const float* Wih    = (const float*)d_in[9];
  const float* Whh    = (const float*)d_in[10];
  const float* bih    = (const float*)d_in[11];
  const float* bhh    = (const float*)d_in[12];
  const float* out_W  = (const float*)d_in[13];
  const float* out_b  = (const float*)d_in[14];

  float* out      = (float*)d_out;
  float* out0     = out;                          // 2048
  float* out_h    = out + NB;                     // B*H
  float* out_attn = out + NB + (size_t)NB*NH;     // B*L

  float* wsf    = (float*)d_ws;
  float* stats  = wsf;              // 16
  float* p      = wsf + 16;         // 256
  float* q      = wsf + 272;        // 256
  float* p2     = wsf + 528;        // 512
  float* q2     = wsf + 1040;       // 512
  float* logits = wsf + 2048;       // [2048][256] fp32
  ushort_t* usb = (ushort_t*)(wsf + 526400);
  ushort_t* A2  = usb;              // [2048][1024] bf16: [xt | h0]
  ushort_t* ABF = usb + 2097152;    // [2048][512]  bf16 attn_applied
  ushort_t* WTA = usb + 3145728;    // [256][512]
  ushort_t* WTC = usb + 3276800;    // [512][512]
  ushort_t* WTG = usb + 3538944;    // [2048][1024]

  kTiny<<<53, 256, 0, stream>>>(emb_W, emb_b, attn_W, comb_W, out_b,
                                WTA, stats, p, q, p2, q2, out0);
  kLogits<<<dim3(16, 4), 256, 0, stream>>>(hidden, WTA, x, stats, p, q,
                                           attn_b, logits);
  kStreamMega<<<3136, 256, 0, stream>>>(hidden, Wih, Whh, comb_W, logits, enc,
                                        A2, WTG, WTC, out_attn, ABF);
  kComb<<<dim3(16, 8), 256, 0, stream>>>(ABF, WTC, x, stats, p2, q2, comb_b, A2);
  kGRU<<<dim3(16, 16), 256, 0, stream>>>(A2, WTG, bih, bhh, hidden, out_W,
                                         out_h, out0);
}

// Round 11
// 262.273 us; speedup vs baseline: 1.2785x; 1.0716x over previous
//
#include <hip/hip_runtime.h>
#include <math.h>

#define NB 2048
#define NL 256
#define NH 512

typedef unsigned short ushort_t;
typedef unsigned int uint_t;
typedef short s16x8 __attribute__((ext_vector_type(8)));
typedef short s16x4 __attribute__((ext_vector_type(4)));
typedef float f32x4 __attribute__((ext_vector_type(4)));

__device__ __forceinline__ float wsum(float v){
  #pragma unroll
  for (int o = 32; o; o >>= 1) v += __shfl_xor(v, o);
  return v;
}
__device__ __forceinline__ float wmax(float v){
  #pragma unroll
  for (int o = 32; o; o >>= 1) v = fmaxf(v, __shfl_xor(v, o));
  return v;
}
__device__ __forceinline__ ushort_t f2bf(float f){
  union { float f; unsigned u; } v; v.f = f;
  unsigned r = v.u + 0x7fffu + ((v.u >> 16) & 1u);
  return (ushort_t)(r >> 16);
}

// ---------------------------------------------------------------------------
// kTiny (53 blocks x 256): pre-stream minimal prep.
//  bid <  32: WTA[c][k] = bf16 attn_W_bottom^T  (256x512)
//  bid <  44: p,q (attn top rank-2, 4 blk) / p2,q2 (comb top rank-2, 8 blk)
//  bid == 44: stats = {mW, mb, Su2, Suv, Sv2}
//  bid >  44: out0[b] = out_b[0] (8 blk)
// ---------------------------------------------------------------------------
__global__ __launch_bounds__(256)
void kTiny(const float* __restrict__ eW, const float* __restrict__ eb,
           const float* __restrict__ attn_W, const float* __restrict__ comb_W,
           const float* __restrict__ out_b,
           ushort_t* __restrict__ WTA, float* __restrict__ stats,
           float* __restrict__ p, float* __restrict__ q,
           float* __restrict__ p2, float* __restrict__ q2,
           float* __restrict__ out0)
{
  const int bid = blockIdx.x, tid = threadIdx.x;
  if (bid < 32) {                        // WTA bf16 transpose
    const int bx = bid & 3, by = bid >> 2;
    const int c = bx*64 + (tid & 63);
    const int ksub = by*64 + (tid >> 6)*16;
    ushort_t vals[16];
    #pragma unroll
    for (int kk = 0; kk < 16; ++kk)
      vals[kk] = f2bf(attn_W[(size_t)(512 + ksub + kk)*NL + c]);
    *(s16x8*)&WTA[(size_t)c*512 + ksub]     = *(s16x8*)&vals[0];
    *(s16x8*)&WTA[(size_t)c*512 + ksub + 8] = *(s16x8*)&vals[8];
    return;
  }
  if (bid > 44) {                        // out0 init
    out0[(bid-45)*256 + tid] = out_b[0];
    return;
  }
  // rank-2 projections + stats
  {
    __shared__ float rw[4], rb[4];
    __shared__ float pa[4][64], pb[4][64];
    const int lane = tid & 63, wv = tid >> 6;
    float swv = eW[tid] + eW[tid + 256];
    float sbv = eb[tid] + eb[tid + 256];
    swv = wsum(swv); sbv = wsum(sbv);
    if (lane == 0) { rw[wv] = swv; rb[wv] = sbv; }
    __syncthreads();
    const float mW = (rw[0]+rw[1]+rw[2]+rw[3]) * (1.f/NH);
    const float mb = (rb[0]+rb[1]+rb[2]+rb[3]) * (1.f/NH);

    if (bid == 44) {
      float u0 = eW[tid]-mW, u1 = eW[tid+256]-mW;
      float v0 = eb[tid]-mb, v1 = eb[tid+256]-mb;
      float s2 = u0*u0 + u1*u1, s3 = u0*v0 + u1*v1, s4 = v0*v0 + v1*v1;
      s2 = wsum(s2); s3 = wsum(s3); s4 = wsum(s4);
      if (lane == 0) { pa[0][wv] = s2; pa[1][wv] = s3; pa[2][wv] = s4; }
      __syncthreads();
      if (tid == 0) {
        stats[0] = mW; stats[1] = mb;
        stats[2] = pa[0][0]+pa[0][1]+pa[0][2]+pa[0][3];
        stats[3] = pa[1][0]+pa[1][1]+pa[1][2]+pa[1][3];
        stats[4] = pa[2][0]+pa[2][1]+pa[2][2]+pa[2][3];
      }
      return;
    }
    const int bid2 = bid - 32;
    const float* Wsrc; int ldw, c0; float *op, *oq;
    if (bid2 < 4) { Wsrc = attn_W; ldw = NL; c0 = bid2*64;     op = p  + c0; oq = q  + c0; }
    else          { Wsrc = comb_W; ldw = NH; c0 = (bid2-4)*64; op = p2 + c0; oq = q2 + c0; }
    const int c = c0 + lane;
    const int hc = tid >> 6;
    float ap = 0.f, aq = 0.f;
    #pragma unroll 4
    for (int h = hc*128; h < hc*128 + 128; ++h) {
      float w = Wsrc[(size_t)h*ldw + c];
      ap = fmaf(eW[h]-mW, w, ap);
      aq = fmaf(eb[h]-mb, w, aq);
    }
    pa[hc][lane] = ap; pb[hc][lane] = aq;
    __syncthreads();
    if (hc == 0) {
      op[lane] = pa[0][lane]+pa[1][lane]+pa[2][lane]+pa[3][lane];
      oq[lane] = pb[0][lane]+pb[1][lane]+pb[2][lane]+pb[3][lane];
    }
  }
}

// ---------------------------------------------------------------------------
// kLogits: 128x64 tile MFMA GEMM, A staged DIRECTLY from fp32 hidden
// (cvt during staging). B = WTA bf16. Epilogue: logits = acc + attn_b + rank2
// -> fp32 [2048][256]. grid(16,4).
// ---------------------------------------------------------------------------
__global__ __launch_bounds__(256)
void kLogits(const float* __restrict__ hidden, const ushort_t* __restrict__ WTA,
             const float* __restrict__ x, const float* __restrict__ stats,
             const float* __restrict__ p, const float* __restrict__ q,
             const float* __restrict__ attn_b, float* __restrict__ logits)
{
  __shared__ ushort_t As[128][72];
  __shared__ ushort_t Bs[64][72];
  const int tid = threadIdx.x, lane = tid & 63, wr = tid >> 6;
  const int m0 = blockIdx.x * 128, n0 = blockIdx.y * 64;

  f32x4 acc[2][4];
  #pragma unroll
  for (int i = 0; i < 2; ++i)
    #pragma unroll
    for (int j = 0; j < 4; ++j)
      acc[i][j] = (f32x4){0.f,0.f,0.f,0.f};

  const int srow = tid >> 3, scol = (tid & 7) * 8;
  for (int kt = 0; kt < 512; kt += 64) {
    __syncthreads();
    #pragma unroll
    for (int it = 0; it < 4; ++it) {
      const int r = srow + it*32;
      const float* hp = hidden + (size_t)(m0+r)*NH + kt + scol;
      float4 v0 = *(const float4*)hp;
      float4 v1 = *(const float4*)(hp + 4);
      s16x8 o;
      o[0]=f2bf(v0.x); o[1]=f2bf(v0.y); o[2]=f2bf(v0.z); o[3]=f2bf(v0.w);
      o[4]=f2bf(v1.x); o[5]=f2bf(v1.y); o[6]=f2bf(v1.z); o[7]=f2bf(v1.w);
      *(s16x8*)&As[r][scol] = o;
    }
    #pragma unroll
    for (int it = 0; it < 2; ++it) {
      const int r = srow + it*32;
      *(s16x8*)&Bs[r][scol] = *(const s16x8*)&WTA[(size_t)(n0+r)*512 + kt + scol];
    }
    __syncthreads();
    #pragma unroll
    for (int ks = 0; ks < 2; ++ks) {
      const int ko = ks*32 + (lane >> 4)*8;
      s16x8 af[2], bfr[4];
      #pragma unroll
      for (int i = 0; i < 2; ++i) af[i]  = *(const s16x8*)&As[wr*32 + i*16 + (lane & 15)][ko];
      #pragma unroll
      for (int j = 0; j < 4; ++j) bfr[j] = *(const s16x8*)&Bs[j*16 + (lane & 15)][ko];
      #pragma unroll
      for (int i = 0; i < 2; ++i)
        #pragma unroll
        for (int j = 0; j < 4; ++j)
          acc[i][j] = __builtin_amdgcn_mfma_f32_16x16x32_bf16(af[i], bfr[j], acc[i][j], 0, 0, 0);
    }
  }

  const float S2 = stats[2], S3 = stats[3], S4 = stats[4];
  #pragma unroll
  for (int i = 0; i < 2; ++i) {
    #pragma unroll
    for (int reg = 0; reg < 4; ++reg) {
      const int row = m0 + wr*32 + i*16 + ((lane >> 4) << 2) + reg;
      const float xv = x[row];
      const float rs = rsqrtf((xv*xv*S2 + 2.f*xv*S3 + S4)*(1.0f/NH) + 1e-5f);
      const float al = xv*rs, be = rs;
      #pragma unroll
      for (int j = 0; j < 4; ++j) {
        const int col = n0 + j*16 + (lane & 15);
        logits[(size_t)row*NL + col] = acc[i][j][reg] + attn_b[col] + al*p[col] + be*q[col];
      }
    }
  }
}

// ---------------------------------------------------------------------------
// kStreamMega (3136 blocks x 256): STREAM BLOCKS FIRST (bid < 2048) so they
// fill the machine; prep blocks (A2-h0, WTG, WTC) dispatch into the stream's
// spare slots as stream blocks retire (r9 had them first = serialized).
//  bid < 2048 (b = bid): softmax(logits[b]) -> attn_out + wl; then
//       a[512] = sum_l wl[l]*enc[b,l,:] -> bf16 ABF (nt loads on enc).
//  bid < 2560: hidden fp32 -> bf16 into A2 right half (lda 1024)
//  bid < 3072: WTG[n][k] bf16 gate-interleaved blockdiag GRU weight
//  bid < 3136: WTC[c][k] = bf16 comb_W_bottom^T (512x512)
// ---------------------------------------------------------------------------
__global__ __launch_bounds__(256)
void kStreamMega(const float* __restrict__ hidden,
                 const float* __restrict__ Wih, const float* __restrict__ Whh,
                 const float* __restrict__ comb_W,
                 const float* __restrict__ logits, const float* __restrict__ enc,
                 ushort_t* __restrict__ A2, ushort_t* __restrict__ WTG,
                 ushort_t* __restrict__ WTC,
                 float* __restrict__ attn_out, ushort_t* __restrict__ ABF)
{
  const int bid = blockIdx.x, tid = threadIdx.x;
  if (bid < 2048) {                      // ---- stream block
    __shared__ float wl[NL];
    __shared__ __align__(16) float4 ps[128];
    __shared__ float sred[4];
    const int lane = tid & 63, wv = tid >> 6;
    const int b = bid;

    float lg = logits[(size_t)b*NL + tid];
    float m = wmax(lg);
    if (lane == 0) sred[wv] = m;
    __syncthreads();
    m = fmaxf(fmaxf(sred[0], sred[1]), fmaxf(sred[2], sred[3]));
    float e = expf(lg - m);
    float s = wsum(e);
    __syncthreads();
    if (lane == 0) sred[wv] = s;
    __syncthreads();
    const float inv = 1.f / (sred[0] + sred[1] + sred[2] + sred[3]);
    e *= inv;
    wl[tid] = e;
    attn_out[(size_t)b*NL + tid] = e;
    __syncthreads();

    const int col = tid & 127, half = tid >> 7;
    const f32x4* ep = (const f32x4*)(enc + (size_t)b*NL*NH);
    float4 acc = {0.f,0.f,0.f,0.f};
    #pragma unroll 4
    for (int l = half*128; l < half*128 + 128; ++l) {
      float w = wl[l];
      f32x4 ev = __builtin_nontemporal_load(ep + l*(NH/4) + col);
      acc.x = fmaf(w,ev[0],acc.x); acc.y = fmaf(w,ev[1],acc.y);
      acc.z = fmaf(w,ev[2],acc.z); acc.w = fmaf(w,ev[3],acc.w);
    }
    if (half == 0) ps[col] = acc;
    __syncthreads();
    if (half == 1) {
      float4 o = ps[col];
      o.x += acc.x; o.y += acc.y; o.z += acc.z; o.w += acc.w;
      s16x4 ov; ov[0]=f2bf(o.x); ov[1]=f2bf(o.y); ov[2]=f2bf(o.z); ov[3]=f2bf(o.w);
      *(s16x4*)&ABF[(size_t)b*NH + col*4] = ov;
    }
    return;
  }
  if (bid < 2560) {                      // hidden -> bf16 A2 right half
    const int idx = ((bid-2048)*256 + tid) * 8;
    const int b = idx >> 9, h = idx & 511;
    float4 v0 = *(const float4*)(hidden + idx);
    float4 v1 = *(const float4*)(hidden + idx + 4);
    s16x8 o;
    o[0]=f2bf(v0.x); o[1]=f2bf(v0.y); o[2]=f2bf(v0.z); o[3]=f2bf(v0.w);
    o[4]=f2bf(v1.x); o[5]=f2bf(v1.y); o[6]=f2bf(v1.z); o[7]=f2bf(v1.w);
    *(s16x8*)&A2[(size_t)b*1024 + 512 + h] = o;
    return;
  }
  if (bid < 3072) {                      // WTG bf16 gate-blockdiag
    const int b2 = bid - 2560, bx = b2 & 31, by = b2 >> 5;
    const int n = bx*64 + (tid & 63);
    const int ksub = by*64 + (tid >> 6)*16;
    const int g = n >> 6, t = (n >> 4) & 3, c = (g << 4) | (n & 15);
    const int sc = (t == 0) ? c : (t == 1) ? (512 + c) : (1024 + c);
    ushort_t vals[16];
    #pragma unroll
    for (int kk = 0; kk < 16; ++kk) {
      int k = ksub + kk;
      float v;
      if (k < 512) v = (t == 3) ? 0.f : Wih[(size_t)k*1536 + sc];
      else         v = (t == 2) ? 0.f : Whh[(size_t)(k-512)*1536 + sc];
      vals[kk] = f2bf(v);
    }
    *(s16x8*)&WTG[(size_t)n*1024 + ksub]     = *(s16x8*)&vals[0];
    *(s16x8*)&WTG[(size_t)n*1024 + ksub + 8] = *(s16x8*)&vals[8];
    return;
  }
  {                                      // WTC bf16 transpose
    const int b2 = bid - 3072, bx = b2 & 7, by = b2 >> 3;
    const int c = bx*64 + (tid & 63);
    const int ksub = by*64 + (tid >> 6)*16;
    ushort_t vals[16];
    #pragma unroll
    for (int kk = 0; kk < 16; ++kk)
      vals[kk] = f2bf(comb_W[(size_t)(512 + ksub + kk)*NH + c]);
    *(s16x8*)&WTC[(size_t)c*512 + ksub]     = *(s16x8*)&vals[0];
    *(s16x8*)&WTC[(size_t)c*512 + ksub + 8] = *(s16x8*)&vals[8];
  }
}

// ---------------------------------------------------------------------------
// kComb: 128x64 tile. xt = relu(ABF @ WTC^T + comb_b + rank2) -> bf16 A2 left
// (ld 1024). grid(16,8).
// ---------------------------------------------------------------------------
__global__ __launch_bounds__(256)
void kComb(const ushort_t* __restrict__ ABF, const ushort_t* __restrict__ WTC,
           const float* __restrict__ x, const float* __restrict__ stats,
           const float* __restrict__ p2, const float* __restrict__ q2,
           const float* __restrict__ comb_b, ushort_t* __restrict__ A2)
{
  __shared__ ushort_t As[128][72];
  __shared__ ushort_t Bs[64][72];
  const int tid = threadIdx.x, lane = tid & 63, wr = tid >> 6;
  const int m0 = blockIdx.x * 128, n0 = blockIdx.y * 64;

  f32x4 acc[2][4];
  #pragma unroll
  for (int i = 0; i < 2; ++i)
    #pragma unroll
    for (int j = 0; j < 4; ++j)
      acc[i][j] = (f32x4){0.f,0.f,0.f,0.f};

  const int srow = tid >> 3, scol = (tid & 7) * 8;
  for (int kt = 0; kt < 512; kt += 64) {
    __syncthreads();
    #pragma unroll
    for (int it = 0; it < 4; ++it) {
      const int r = srow + it*32;
      *(s16x8*)&As[r][scol] = *(const s16x8*)&ABF[(size_t)(m0+r)*512 + kt + scol];
    }
    #pragma unroll
    for (int it = 0; it < 2; ++it) {
      const int r = srow + it*32;
      *(s16x8*)&Bs[r][scol] = *(const s16x8*)&WTC[(size_t)(n0+r)*512 + kt + scol];
    }
    __syncthreads();
    #pragma unroll
    for (int ks = 0; ks < 2; ++ks) {
      const int ko = ks*32 + (lane >> 4)*8;
      s16x8 af[2], bfr[4];
      #pragma unroll
      for (int i = 0; i < 2; ++i) af[i]  = *(const s16x8*)&As[wr*32 + i*16 + (lane & 15)][ko];
      #pragma unroll
      for (int j = 0; j < 4; ++j) bfr[j] = *(const s16x8*)&Bs[j*16 + (lane & 15)][ko];
      #pragma unroll
      for (int i = 0; i < 2; ++i)
        #pragma unroll
        for (int j = 0; j < 4; ++j)
          acc[i][j] = __builtin_amdgcn_mfma_f32_16x16x32_bf16(af[i], bfr[j], acc[i][j], 0, 0, 0);
    }
  }

  const float S2 = stats[2], S3 = stats[3], S4 = stats[4];
  #pragma unroll
  for (int i = 0; i < 2; ++i) {
    #pragma unroll
    for (int reg = 0; reg < 4; ++reg) {
      const int row = m0 + wr*32 + i*16 + ((lane >> 4) << 2) + reg;
      const float xv = x[row];
      const float rs = rsqrtf((xv*xv*S2 + 2.f*xv*S3 + S4)*(1.0f/NH) + 1e-5f);
      const float al = xv*rs, be = rs;
      #pragma unroll
      for (int j = 0; j < 4; ++j) {
        const int col = n0 + j*16 + (lane & 15);
        float v = acc[i][j][reg] + comb_b[col] + al*p2[col] + be*q2[col];
        A2[(size_t)row*1024 + col] = f2bf(fmaxf(v, 0.f));
      }
    }
  }
}

// ---------------------------------------------------------------------------
// kGRU: 128x64 tile, 4 waves (4x1) — r7's proven config, 512 blocks = 2/CU.
// A = [xt|h0] bf16 (lda 1024), Bt = WTG (2048x1024). Epilogue: GRU gates ->
// h_new fp32 + fused out0 atomic reduce (out0 pre-init to out_b by kTiny).
// ---------------------------------------------------------------------------
__global__ __launch_bounds__(256)
void kGRU(const ushort_t* __restrict__ A, const ushort_t* __restrict__ Bt,
          const float* __restrict__ bih, const float* __restrict__ bhh,
          const float* __restrict__ hidden, const float* __restrict__ out_W,
          float* __restrict__ h_out, float* __restrict__ out0)
{
  __shared__ ushort_t As[128][72];
  __shared__ ushort_t Bs[64][72];
  const int tid = threadIdx.x, lane = tid & 63, wr = tid >> 6;
  const int m0 = blockIdx.x * 128, n0 = blockIdx.y * 64;
  const int K = 1024;

  f32x4 acc[2][4];
  #pragma unroll
  for (int i = 0; i < 2; ++i)
    #pragma unroll
    for (int j = 0; j < 4; ++j)
      acc[i][j] = (f32x4){0.f,0.f,0.f,0.f};

  const int srow = tid >> 3, scol = (tid & 7) * 8;
  for (int kt = 0; kt < K; kt += 64) {
    __syncthreads();
    #pragma unroll
    for (int it = 0; it < 4; ++it) {
      const int r = srow + it*32;
      *(s16x8*)&As[r][scol] = *(const s16x8*)&A[(size_t)(m0+r)*1024 + kt + scol];
    }
    #pragma unroll
    for (int it = 0; it < 2; ++it) {
      const int r = srow + it*32;
      *(s16x8*)&Bs[r][scol] = *(const s16x8*)&Bt[(size_t)(n0+r)*K + kt + scol];
    }
    __syncthreads();
    #pragma unroll
    for (int ks = 0; ks < 2; ++ks) {
      const int ko = ks*32 + (lane >> 4)*8;
      s16x8 af[2], bfr[4];
      #pragma unroll
      for (int i = 0; i < 2; ++i) af[i]  = *(const s16x8*)&As[wr*32 + i*16 + (lane & 15)][ko];
      #pragma unroll
      for (int j = 0; j < 4; ++j) bfr[j] = *(const s16x8*)&Bs[j*16 + (lane & 15)][ko];
      #pragma unroll
      for (int i = 0; i < 2; ++i)
        #pragma unroll
        for (int j = 0; j < 4; ++j)
          acc[i][j] = __builtin_amdgcn_mfma_f32_16x16x32_bf16(af[i], bfr[j], acc[i][j], 0, 0, 0);
    }
  }

  const int g = n0 >> 6;
  const int hcol = (g << 4) | (lane & 15);
  const float b_r = bih[hcol]        + bhh[hcol];
  const float b_z = bih[512 + hcol]  + bhh[512 + hcol];
  const float b_i = bih[1024 + hcol];
  const float b_h = bhh[1024 + hcol];
  const float ow  = out_W[hcol];
  #pragma unroll
  for (int i = 0; i < 2; ++i) {
    #pragma unroll
    for (int reg = 0; reg < 4; ++reg) {
      const int row = m0 + wr*32 + i*16 + ((lane >> 4) << 2) + reg;
      float rv = 1.f / (1.f + expf(-(acc[i][0][reg] + b_r)));
      float zv = 1.f / (1.f + expf(-(acc[i][1][reg] + b_z)));
      float nv = tanhf(acc[i][2][reg] + b_i + rv * (acc[i][3][reg] + b_h));
      float h0v = hidden[(size_t)row*NH + hcol];
      float hn = nv + zv * (h0v - nv);
      h_out[(size_t)row*NH + hcol] = hn;
      float partial = hn * ow;
      #pragma unroll
      for (int o = 1; o < 16; o <<= 1) partial += __shfl_xor(partial, o);
      if ((lane & 15) == 0) atomicAdd(&out0[row], partial);
    }
  }
}

// ---------------------------------------------------------------------------
extern "C" void kernel_launch(void* const* d_in, const int* in_sizes, int n_in,
                              void* d_out, int out_size, void* d_ws, size_t ws_size,
                              hipStream_t stream)
{
  const float* x      = (const float*)d_in[0];
  const float* hidden = (const float*)d_in[1];
  const float* enc    = (const float*)d_in[2];
  const float* emb_W  = (const float*)d_in[3];
  const float* emb_b  = (const float*)d_in[4];
  const float* attn_W = (const float*)d_in[5];
  const float* attn_b = (const float*)d_in[6];
  const float* comb_W = (const float*)d_in[7];
  const float* comb_b = (const float*)d_in[8];
  const float* Wih    = (const float*)d_in[9];
  const float* Whh    = (const float*)d_in[10];
  const float* bih    = (const float*)d_in[11];
  const float* bhh    = (const float*)d_in[12];
  const float* out_W  = (const float*)d_in[13];
  const float* out_b  = (const float*)d_in[14];

  float* out      = (float*)d_out;
  float* out0     = out;                          // 2048
  float* out_h    = out + NB;                     // B*H
  float* out_attn = out + NB + (size_t)NB*NH;     // B*L

  float* wsf    = (float*)d_ws;
  float* stats  = wsf;              // 16
  float* p      = wsf + 16;         // 256
  float* q      = wsf + 272;        // 256
  float* p2     = wsf + 528;        // 512
  float* q2     = wsf + 1040;       // 512
  float* logits = wsf + 2048;       // [2048][256] fp32
  ushort_t* usb = (ushort_t*)(wsf + 526400);
  ushort_t* A2  = usb;              // [2048][1024] bf16: [xt | h0]
  ushort_t* ABF = usb + 2097152;    // [2048][512]  bf16 attn_applied
  ushort_t* WTA = usb + 3145728;    // [256][512]
  ushort_t* WTC = usb + 3276800;    // [512][512]
  ushort_t* WTG = usb + 3538944;    // [2048][1024]

  kTiny<<<53, 256, 0, stream>>>(emb_W, emb_b, attn_W, comb_W, out_b,
                                WTA, stats, p, q, p2, q2, out0);
  kLogits<<<dim3(16, 4), 256, 0, stream>>>(hidden, WTA, x, stats, p, q,
                                           attn_b, logits);
  kStreamMega<<<3136, 256, 0, stream>>>(hidden, Wih, Whh, comb_W, logits, enc,
                                        A2, WTG, WTC, out_attn, ABF);
  kComb<<<dim3(16, 8), 256, 0, stream>>>(ABF, WTC, x, stats, p2, q2, comb_b, A2);
  kGRU<<<dim3(16, 32), 256, 0, stream>>>(A2, WTG, bih, bhh, hidden, out_W,
                                         out_h, out0);
}

// Round 12
// 245.964 us; speedup vs baseline: 1.3633x; 1.0663x over previous
//
#include <hip/hip_runtime.h>
#include <math.h>

#define NB 2048
#define NL 256
#define NH 512

typedef unsigned short ushort_t;
typedef unsigned int uint_t;
typedef short s16x8 __attribute__((ext_vector_type(8)));
typedef short s16x4 __attribute__((ext_vector_type(4)));
typedef float f32x4 __attribute__((ext_vector_type(4)));

__device__ __forceinline__ float wsum(float v){
  #pragma unroll
  for (int o = 32; o; o >>= 1) v += __shfl_xor(v, o);
  return v;
}
__device__ __forceinline__ float wmax(float v){
  #pragma unroll
  for (int o = 32; o; o >>= 1) v = fmaxf(v, __shfl_xor(v, o));
  return v;
}
__device__ __forceinline__ ushort_t f2bf(float f){
  union { float f; unsigned u; } v; v.f = f;
  unsigned r = v.u + 0x7fffu + ((v.u >> 16) & 1u);
  return (ushort_t)(r >> 16);
}

// ---------------------------------------------------------------------------
// kTiny (37 blocks x 256): minimal pre-logits prep.
//  bid < 32: WTA[c][k] = bf16 attn_W_bottom^T  (256x512)
//  bid < 36: p,q (attn top rank-2)
//  bid ==36: stats = {mW, mb, Su2, Suv, Sv2}
// (p2/q2 + out0-init moved to kStreamMega tail — consumed only by kComb/kGRU)
// ---------------------------------------------------------------------------
__global__ __launch_bounds__(256)
void kTiny(const float* __restrict__ eW, const float* __restrict__ eb,
           const float* __restrict__ attn_W,
           ushort_t* __restrict__ WTA, float* __restrict__ stats,
           float* __restrict__ p, float* __restrict__ q)
{
  const int bid = blockIdx.x, tid = threadIdx.x;
  if (bid < 32) {                        // WTA bf16 transpose
    const int bx = bid & 3, by = bid >> 2;
    const int c = bx*64 + (tid & 63);
    const int ksub = by*64 + (tid >> 6)*16;
    ushort_t vals[16];
    #pragma unroll
    for (int kk = 0; kk < 16; ++kk)
      vals[kk] = f2bf(attn_W[(size_t)(512 + ksub + kk)*NL + c]);
    *(s16x8*)&WTA[(size_t)c*512 + ksub]     = *(s16x8*)&vals[0];
    *(s16x8*)&WTA[(size_t)c*512 + ksub + 8] = *(s16x8*)&vals[8];
    return;
  }
  // rank-2 projections + stats
  {
    __shared__ float rw[4], rb[4];
    __shared__ float pa[4][64], pb[4][64];
    const int lane = tid & 63, wv = tid >> 6;
    float swv = eW[tid] + eW[tid + 256];
    float sbv = eb[tid] + eb[tid + 256];
    swv = wsum(swv); sbv = wsum(sbv);
    if (lane == 0) { rw[wv] = swv; rb[wv] = sbv; }
    __syncthreads();
    const float mW = (rw[0]+rw[1]+rw[2]+rw[3]) * (1.f/NH);
    const float mb = (rb[0]+rb[1]+rb[2]+rb[3]) * (1.f/NH);

    if (bid == 36) {
      float u0 = eW[tid]-mW, u1 = eW[tid+256]-mW;
      float v0 = eb[tid]-mb, v1 = eb[tid+256]-mb;
      float s2 = u0*u0 + u1*u1, s3 = u0*v0 + u1*v1, s4 = v0*v0 + v1*v1;
      s2 = wsum(s2); s3 = wsum(s3); s4 = wsum(s4);
      if (lane == 0) { pa[0][wv] = s2; pa[1][wv] = s3; pa[2][wv] = s4; }
      __syncthreads();
      if (tid == 0) {
        stats[0] = mW; stats[1] = mb;
        stats[2] = pa[0][0]+pa[0][1]+pa[0][2]+pa[0][3];
        stats[3] = pa[1][0]+pa[1][1]+pa[1][2]+pa[1][3];
        stats[4] = pa[2][0]+pa[2][1]+pa[2][2]+pa[2][3];
      }
      return;
    }
    const int c = (bid - 32)*64 + lane;
    const int hc = tid >> 6;
    float ap = 0.f, aq = 0.f;
    #pragma unroll 4
    for (int h = hc*128; h < hc*128 + 128; ++h) {
      float w = attn_W[(size_t)h*NL + c];
      ap = fmaf(eW[h]-mW, w, ap);
      aq = fmaf(eb[h]-mb, w, aq);
    }
    pa[hc][lane] = ap; pb[hc][lane] = aq;
    __syncthreads();
    if (hc == 0) {
      p[c] = pa[0][lane]+pa[1][lane]+pa[2][lane]+pa[3][lane];
      q[c] = pb[0][lane]+pb[1][lane]+pb[2][lane]+pb[3][lane];
    }
  }
}

// ---------------------------------------------------------------------------
// kLogits: 128x64 tile MFMA GEMM, A staged DIRECTLY from fp32 hidden
// (cvt during staging). B = WTA bf16. Epilogue: logits = acc + attn_b + rank2
// -> fp32 [2048][256]. grid(16,4).
// ---------------------------------------------------------------------------
__global__ __launch_bounds__(256)
void kLogits(const float* __restrict__ hidden, const ushort_t* __restrict__ WTA,
             const float* __restrict__ x, const float* __restrict__ stats,
             const float* __restrict__ p, const float* __restrict__ q,
             const float* __restrict__ attn_b, float* __restrict__ logits)
{
  __shared__ ushort_t As[128][72];
  __shared__ ushort_t Bs[64][72];
  const int tid = threadIdx.x, lane = tid & 63, wr = tid >> 6;
  const int m0 = blockIdx.x * 128, n0 = blockIdx.y * 64;

  f32x4 acc[2][4];
  #pragma unroll
  for (int i = 0; i < 2; ++i)
    #pragma unroll
    for (int j = 0; j < 4; ++j)
      acc[i][j] = (f32x4){0.f,0.f,0.f,0.f};

  const int srow = tid >> 3, scol = (tid & 7) * 8;
  for (int kt = 0; kt < 512; kt += 64) {
    __syncthreads();
    #pragma unroll
    for (int it = 0; it < 4; ++it) {
      const int r = srow + it*32;
      const float* hp = hidden + (size_t)(m0+r)*NH + kt + scol;
      float4 v0 = *(const float4*)hp;
      float4 v1 = *(const float4*)(hp + 4);
      s16x8 o;
      o[0]=f2bf(v0.x); o[1]=f2bf(v0.y); o[2]=f2bf(v0.z); o[3]=f2bf(v0.w);
      o[4]=f2bf(v1.x); o[5]=f2bf(v1.y); o[6]=f2bf(v1.z); o[7]=f2bf(v1.w);
      *(s16x8*)&As[r][scol] = o;
    }
    #pragma unroll
    for (int it = 0; it < 2; ++it) {
      const int r = srow + it*32;
      *(s16x8*)&Bs[r][scol] = *(const s16x8*)&WTA[(size_t)(n0+r)*512 + kt + scol];
    }
    __syncthreads();
    #pragma unroll
    for (int ks = 0; ks < 2; ++ks) {
      const int ko = ks*32 + (lane >> 4)*8;
      s16x8 af[2], bfr[4];
      #pragma unroll
      for (int i = 0; i < 2; ++i) af[i]  = *(const s16x8*)&As[wr*32 + i*16 + (lane & 15)][ko];
      #pragma unroll
      for (int j = 0; j < 4; ++j) bfr[j] = *(const s16x8*)&Bs[j*16 + (lane & 15)][ko];
      #pragma unroll
      for (int i = 0; i < 2; ++i)
        #pragma unroll
        for (int j = 0; j < 4; ++j)
          acc[i][j] = __builtin_amdgcn_mfma_f32_16x16x32_bf16(af[i], bfr[j], acc[i][j], 0, 0, 0);
    }
  }

  const float S2 = stats[2], S3 = stats[3], S4 = stats[4];
  #pragma unroll
  for (int i = 0; i < 2; ++i) {
    #pragma unroll
    for (int reg = 0; reg < 4; ++reg) {
      const int row = m0 + wr*32 + i*16 + ((lane >> 4) << 2) + reg;
      const float xv = x[row];
      const float rs = rsqrtf((xv*xv*S2 + 2.f*xv*S3 + S4)*(1.0f/NH) + 1e-5f);
      const float al = xv*rs, be = rs;
      #pragma unroll
      for (int j = 0; j < 4; ++j) {
        const int col = n0 + j*16 + (lane & 15);
        logits[(size_t)row*NL + col] = acc[i][j][reg] + attn_b[col] + al*p[col] + be*q[col];
      }
    }
  }
}

// ---------------------------------------------------------------------------
// kStreamMega (3152 blocks x 256): STREAM BLOCKS FIRST (bid < 2048); prep
// blocks dispatch into the stream's spare slots as stream blocks retire.
//  bid < 2048: softmax(logits[b]) -> attn_out + wl; a = sum_l wl*enc -> ABF
//  bid < 2560: hidden fp32 -> bf16 into A2 right half (lda 1024)
//  bid < 3072: WTG[n][k] bf16 gate-interleaved blockdiag GRU weight
//  bid < 3136: WTC[c][k] = bf16 comb_W_bottom^T (512x512)
//  bid < 3144: p2,q2 (comb top rank-2)
//  else      : out0[b] = out_b[0]
// ---------------------------------------------------------------------------
__global__ __launch_bounds__(256)
void kStreamMega(const float* __restrict__ hidden,
                 const float* __restrict__ Wih, const float* __restrict__ Whh,
                 const float* __restrict__ comb_W,
                 const float* __restrict__ eW, const float* __restrict__ eb,
                 const float* __restrict__ out_b,
                 const float* __restrict__ logits, const float* __restrict__ enc,
                 ushort_t* __restrict__ A2, ushort_t* __restrict__ WTG,
                 ushort_t* __restrict__ WTC,
                 float* __restrict__ p2, float* __restrict__ q2,
                 float* __restrict__ out0,
                 float* __restrict__ attn_out, ushort_t* __restrict__ ABF)
{
  const int bid = blockIdx.x, tid = threadIdx.x;
  if (bid < 2048) {                      // ---- stream block
    __shared__ float wl[NL];
    __shared__ __align__(16) float4 ps[128];
    __shared__ float sred[4];
    const int lane = tid & 63, wv = tid >> 6;
    const int b = bid;

    float lg = logits[(size_t)b*NL + tid];
    float m = wmax(lg);
    if (lane == 0) sred[wv] = m;
    __syncthreads();
    m = fmaxf(fmaxf(sred[0], sred[1]), fmaxf(sred[2], sred[3]));
    float e = expf(lg - m);
    float s = wsum(e);
    __syncthreads();
    if (lane == 0) sred[wv] = s;
    __syncthreads();
    const float inv = 1.f / (sred[0] + sred[1] + sred[2] + sred[3]);
    e *= inv;
    wl[tid] = e;
    attn_out[(size_t)b*NL + tid] = e;
    __syncthreads();

    const int col = tid & 127, half = tid >> 7;
    const f32x4* ep = (const f32x4*)(enc + (size_t)b*NL*NH);
    float4 acc = {0.f,0.f,0.f,0.f};
    #pragma unroll 4
    for (int l = half*128; l < half*128 + 128; ++l) {
      float w = wl[l];
      f32x4 ev = __builtin_nontemporal_load(ep + l*(NH/4) + col);
      acc.x = fmaf(w,ev[0],acc.x); acc.y = fmaf(w,ev[1],acc.y);
      acc.z = fmaf(w,ev[2],acc.z); acc.w = fmaf(w,ev[3],acc.w);
    }
    if (half == 0) ps[col] = acc;
    __syncthreads();
    if (half == 1) {
      float4 o = ps[col];
      o.x += acc.x; o.y += acc.y; o.z += acc.z; o.w += acc.w;
      s16x4 ov; ov[0]=f2bf(o.x); ov[1]=f2bf(o.y); ov[2]=f2bf(o.z); ov[3]=f2bf(o.w);
      *(s16x4*)&ABF[(size_t)b*NH + col*4] = ov;
    }
    return;
  }
  if (bid < 2560) {                      // hidden -> bf16 A2 right half
    const int idx = ((bid-2048)*256 + tid) * 8;
    const int b = idx >> 9, h = idx & 511;
    float4 v0 = *(const float4*)(hidden + idx);
    float4 v1 = *(const float4*)(hidden + idx + 4);
    s16x8 o;
    o[0]=f2bf(v0.x); o[1]=f2bf(v0.y); o[2]=f2bf(v0.z); o[3]=f2bf(v0.w);
    o[4]=f2bf(v1.x); o[5]=f2bf(v1.y); o[6]=f2bf(v1.z); o[7]=f2bf(v1.w);
    *(s16x8*)&A2[(size_t)b*1024 + 512 + h] = o;
    return;
  }
  if (bid < 3072) {                      // WTG bf16 gate-blockdiag
    const int b2 = bid - 2560, bx = b2 & 31, by = b2 >> 5;
    const int n = bx*64 + (tid & 63);
    const int ksub = by*64 + (tid >> 6)*16;
    const int g = n >> 6, t = (n >> 4) & 3, c = (g << 4) | (n & 15);
    const int sc = (t == 0) ? c : (t == 1) ? (512 + c) : (1024 + c);
    ushort_t vals[16];
    #pragma unroll
    for (int kk = 0; kk < 16; ++kk) {
      int k = ksub + kk;
      float v;
      if (k < 512) v = (t == 3) ? 0.f : Wih[(size_t)k*1536 + sc];
      else         v = (t == 2) ? 0.f : Whh[(size_t)(k-512)*1536 + sc];
      vals[kk] = f2bf(v);
    }
    *(s16x8*)&WTG[(size_t)n*1024 + ksub]     = *(s16x8*)&vals[0];
    *(s16x8*)&WTG[(size_t)n*1024 + ksub + 8] = *(s16x8*)&vals[8];
    return;
  }
  if (bid < 3136) {                      // WTC bf16 transpose
    const int b2 = bid - 3072, bx = b2 & 7, by = b2 >> 3;
    const int c = bx*64 + (tid & 63);
    const int ksub = by*64 + (tid >> 6)*16;
    ushort_t vals[16];
    #pragma unroll
    for (int kk = 0; kk < 16; ++kk)
      vals[kk] = f2bf(comb_W[(size_t)(512 + ksub + kk)*NH + c]);
    *(s16x8*)&WTC[(size_t)c*512 + ksub]     = *(s16x8*)&vals[0];
    *(s16x8*)&WTC[(size_t)c*512 + ksub + 8] = *(s16x8*)&vals[8];
    return;
  }
  if (bid < 3144) {                      // p2,q2 (comb top rank-2)
    __shared__ float rw[4], rb[4];
    __shared__ float pa[4][64], pb[4][64];
    const int lane = tid & 63, wv = tid >> 6;
    float swv = eW[tid] + eW[tid + 256];
    float sbv = eb[tid] + eb[tid + 256];
    swv = wsum(swv); sbv = wsum(sbv);
    if (lane == 0) { rw[wv] = swv; rb[wv] = sbv; }
    __syncthreads();
    const float mW = (rw[0]+rw[1]+rw[2]+rw[3]) * (1.f/NH);
    const float mb = (rb[0]+rb[1]+rb[2]+rb[3]) * (1.f/NH);
    const int c = (bid - 3136)*64 + lane;
    const int hc = tid >> 6;
    float ap = 0.f, aq = 0.f;
    #pragma unroll 4
    for (int h = hc*128; h < hc*128 + 128; ++h) {
      float w = comb_W[(size_t)h*NH + c];
      ap = fmaf(eW[h]-mW, w, ap);
      aq = fmaf(eb[h]-mb, w, aq);
    }
    pa[hc][lane] = ap; pb[hc][lane] = aq;
    __syncthreads();
    if (hc == 0) {
      p2[c] = pa[0][lane]+pa[1][lane]+pa[2][lane]+pa[3][lane];
      q2[c] = pb[0][lane]+pb[1][lane]+pb[2][lane]+pb[3][lane];
    }
    return;
  }
  out0[(bid-3144)*256 + tid] = out_b[0]; // out0 init
}

// ---------------------------------------------------------------------------
// kComb: 128x64 tile. xt = relu(ABF @ WTC^T + comb_b + rank2) -> bf16 A2 left
// (ld 1024). grid(16,8).
// ---------------------------------------------------------------------------
__global__ __launch_bounds__(256)
void kComb(const ushort_t* __restrict__ ABF, const ushort_t* __restrict__ WTC,
           const float* __restrict__ x, const float* __restrict__ stats,
           const float* __restrict__ p2, const float* __restrict__ q2,
           const float* __restrict__ comb_b, ushort_t* __restrict__ A2)
{
  __shared__ ushort_t As[128][72];
  __shared__ ushort_t Bs[64][72];
  const int tid = threadIdx.x, lane = tid & 63, wr = tid >> 6;
  const int m0 = blockIdx.x * 128, n0 = blockIdx.y * 64;

  f32x4 acc[2][4];
  #pragma unroll
  for (int i = 0; i < 2; ++i)
    #pragma unroll
    for (int j = 0; j < 4; ++j)
      acc[i][j] = (f32x4){0.f,0.f,0.f,0.f};

  const int srow = tid >> 3, scol = (tid & 7) * 8;
  for (int kt = 0; kt < 512; kt += 64) {
    __syncthreads();
    #pragma unroll
    for (int it = 0; it < 4; ++it) {
      const int r = srow + it*32;
      *(s16x8*)&As[r][scol] = *(const s16x8*)&ABF[(size_t)(m0+r)*512 + kt + scol];
    }
    #pragma unroll
    for (int it = 0; it < 2; ++it) {
      const int r = srow + it*32;
      *(s16x8*)&Bs[r][scol] = *(const s16x8*)&WTC[(size_t)(n0+r)*512 + kt + scol];
    }
    __syncthreads();
    #pragma unroll
    for (int ks = 0; ks < 2; ++ks) {
      const int ko = ks*32 + (lane >> 4)*8;
      s16x8 af[2], bfr[4];
      #pragma unroll
      for (int i = 0; i < 2; ++i) af[i]  = *(const s16x8*)&As[wr*32 + i*16 + (lane & 15)][ko];
      #pragma unroll
      for (int j = 0; j < 4; ++j) bfr[j] = *(const s16x8*)&Bs[j*16 + (lane & 15)][ko];
      #pragma unroll
      for (int i = 0; i < 2; ++i)
        #pragma unroll
        for (int j = 0; j < 4; ++j)
          acc[i][j] = __builtin_amdgcn_mfma_f32_16x16x32_bf16(af[i], bfr[j], acc[i][j], 0, 0, 0);
    }
  }

  const float S2 = stats[2], S3 = stats[3], S4 = stats[4];
  #pragma unroll
  for (int i = 0; i < 2; ++i) {
    #pragma unroll
    for (int reg = 0; reg < 4; ++reg) {
      const int row = m0 + wr*32 + i*16 + ((lane >> 4) << 2) + reg;
      const float xv = x[row];
      const float rs = rsqrtf((xv*xv*S2 + 2.f*xv*S3 + S4)*(1.0f/NH) + 1e-5f);
      const float al = xv*rs, be = rs;
      #pragma unroll
      for (int j = 0; j < 4; ++j) {
        const int col = n0 + j*16 + (lane & 15);
        float v = acc[i][j][reg] + comb_b[col] + al*p2[col] + be*q2[col];
        A2[(size_t)row*1024 + col] = f2bf(fmaxf(v, 0.f));
      }
    }
  }
}

// ---------------------------------------------------------------------------
// kGRU: 128x64 tile, 4 waves (4x1), 512 blocks = 2/CU. A = [xt|h0] bf16
// (lda 1024), Bt = WTG (2048x1024). Block-diagonal skip: gate j==2 (i_n)
// only has nonzero B for k<512; j==3 (h_n) only for k>=512 — so the K-loop
// is split into two static halves doing 12 MFMAs/K-step instead of 16, and
// the zero B rows are not staged (their LDS content is never read).
// Epilogue: GRU gates -> h_new fp32 + fused out0 atomic reduce.
// ---------------------------------------------------------------------------
__global__ __launch_bounds__(256)
void kGRU(const ushort_t* __restrict__ A, const ushort_t* __restrict__ Bt,
          const float* __restrict__ bih, const float* __restrict__ bhh,
          const float* __restrict__ hidden, const float* __restrict__ out_W,
          float* __restrict__ h_out, float* __restrict__ out0)
{
  __shared__ ushort_t As[128][72];
  __shared__ ushort_t Bs[64][72];
  const int tid = threadIdx.x, lane = tid & 63, wr = tid >> 6;
  const int m0 = blockIdx.x * 128, n0 = blockIdx.y * 64;

  f32x4 acc[2][4];
  #pragma unroll
  for (int i = 0; i < 2; ++i)
    #pragma unroll
    for (int j = 0; j < 4; ++j)
      acc[i][j] = (f32x4){0.f,0.f,0.f,0.f};

  const int srow = tid >> 3, scol = (tid & 7) * 8;

  // ---- K half 1: k in [0,512), active gates j = 0,1,2 (B rows t==3 zero)
  for (int kt = 0; kt < 512; kt += 64) {
    __syncthreads();
    #pragma unroll
    for (int it = 0; it < 4; ++it) {
      const int r = srow + it*32;
      *(s16x8*)&As[r][scol] = *(const s16x8*)&A[(size_t)(m0+r)*1024 + kt + scol];
    }
    { // B rows 0..31 (t=0,1) always; rows 32..47 (t=2) only — skip 48..63
      *(s16x8*)&Bs[srow][scol] = *(const s16x8*)&Bt[(size_t)(n0+srow)*1024 + kt + scol];
      if (srow < 16) {
        const int r = srow + 32;
        *(s16x8*)&Bs[r][scol] = *(const s16x8*)&Bt[(size_t)(n0+r)*1024 + kt + scol];
      }
    }
    __syncthreads();
    #pragma unroll
    for (int ks = 0; ks < 2; ++ks) {
      const int ko = ks*32 + (lane >> 4)*8;
      s16x8 af[2], b0, b1, b2;
      #pragma unroll
      for (int i = 0; i < 2; ++i) af[i] = *(const s16x8*)&As[wr*32 + i*16 + (lane & 15)][ko];
      b0 = *(const s16x8*)&Bs[0*16 + (lane & 15)][ko];
      b1 = *(const s16x8*)&Bs[1*16 + (lane & 15)][ko];
      b2 = *(const s16x8*)&Bs[2*16 + (lane & 15)][ko];
      #pragma unroll
      for (int i = 0; i < 2; ++i) {
        acc[i][0] = __builtin_amdgcn_mfma_f32_16x16x32_bf16(af[i], b0, acc[i][0], 0, 0, 0);
        acc[i][1] = __builtin_amdgcn_mfma_f32_16x16x32_bf16(af[i], b1, acc[i][1], 0, 0, 0);
        acc[i][2] = __builtin_amdgcn_mfma_f32_16x16x32_bf16(af[i], b2, acc[i][2], 0, 0, 0);
      }
    }
  }
  // ---- K half 2: k in [512,1024), active gates j = 0,1,3 (B rows t==2 zero)
  for (int kt = 512; kt < 1024; kt += 64) {
    __syncthreads();
    #pragma unroll
    for (int it = 0; it < 4; ++it) {
      const int r = srow + it*32;
      *(s16x8*)&As[r][scol] = *(const s16x8*)&A[(size_t)(m0+r)*1024 + kt + scol];
    }
    { // B rows 0..31 (t=0,1) always; rows 48..63 (t=3) only — skip 32..47
      *(s16x8*)&Bs[srow][scol] = *(const s16x8*)&Bt[(size_t)(n0+srow)*1024 + kt + scol];
      if (srow >= 16) {
        const int r = srow + 32;
        *(s16x8*)&Bs[r][scol] = *(const s16x8*)&Bt[(size_t)(n0+r)*1024 + kt + scol];
      }
    }
    __syncthreads();
    #pragma unroll
    for (int ks = 0; ks < 2; ++ks) {
      const int ko = ks*32 + (lane >> 4)*8;
      s16x8 af[2], b0, b1, b3;
      #pragma unroll
      for (int i = 0; i < 2; ++i) af[i] = *(const s16x8*)&As[wr*32 + i*16 + (lane & 15)][ko];
      b0 = *(const s16x8*)&Bs[0*16 + (lane & 15)][ko];
      b1 = *(const s16x8*)&Bs[1*16 + (lane & 15)][ko];
      b3 = *(const s16x8*)&Bs[3*16 + (lane & 15)][ko];
      #pragma unroll
      for (int i = 0; i < 2; ++i) {
        acc[i][0] = __builtin_amdgcn_mfma_f32_16x16x32_bf16(af[i], b0, acc[i][0], 0, 0, 0);
        acc[i][1] = __builtin_amdgcn_mfma_f32_16x16x32_bf16(af[i], b1, acc[i][1], 0, 0, 0);
        acc[i][3] = __builtin_amdgcn_mfma_f32_16x16x32_bf16(af[i], b3, acc[i][3], 0, 0, 0);
      }
    }
  }

  const int g = n0 >> 6;
  const int hcol = (g << 4) | (lane & 15);
  const float b_r = bih[hcol]        + bhh[hcol];
  const float b_z = bih[512 + hcol]  + bhh[512 + hcol];
  const float b_i = bih[1024 + hcol];
  const float b_h = bhh[1024 + hcol];
  const float ow  = out_W[hcol];
  #pragma unroll
  for (int i = 0; i < 2; ++i) {
    #pragma unroll
    for (int reg = 0; reg < 4; ++reg) {
      const int row = m0 + wr*32 + i*16 + ((lane >> 4) << 2) + reg;
      float rv = 1.f / (1.f + expf(-(acc[i][0][reg] + b_r)));
      float zv = 1.f / (1.f + expf(-(acc[i][1][reg] + b_z)));
      float nv = tanhf(acc[i][2][reg] + b_i + rv * (acc[i][3][reg] + b_h));
      float h0v = hidden[(size_t)row*NH + hcol];
      float hn = nv + zv * (h0v - nv);
      h_out[(size_t)row*NH + hcol] = hn;
      float partial = hn * ow;
      #pragma unroll
      for (int o = 1; o < 16; o <<= 1) partial += __shfl_xor(partial, o);
      if ((lane & 15) == 0) atomicAdd(&out0[row], partial);
    }
  }
}

// ---------------------------------------------------------------------------
extern "C" void kernel_launch(void* const* d_in, const int* in_sizes, int n_in,
                              void* d_out, int out_size, void* d_ws, size_t ws_size,
                              hipStream_t stream)
{
  const float* x      = (const float*)d_in[0];
  const float* hidden = (const float*)d_in[1];
  const float* enc    = (const float*)d_in[2];
  const float* emb_W  = (const float*)d_in[3];
  const float* emb_b  = (const float*)d_in[4];
  const float* attn_W = (const float*)d_in[5];
  const float* attn_b = (const float*)d_in[6];
  const float* comb_W = (const float*)d_in[7];
  const float* comb_b = (const float*)d_in[8];
  const float* Wih    = (const float*)d_in[9];
  const float* Whh    = (const float*)d_in[10];
  const float* bih    = (const float*)d_in[11];
  const float* bhh    = (const float*)d_in[12];
  const float* out_W  = (const float*)d_in[13];
  const float* out_b  = (const float*)d_in[14];

  float* out      = (float*)d_out;
  float* out0     = out;                          // 2048
  float* out_h    = out + NB;                     // B*H
  float* out_attn = out + NB + (size_t)NB*NH;     // B*L

  float* wsf    = (float*)d_ws;
  float* stats  = wsf;              // 16
  float* p      = wsf + 16;         // 256
  float* q      = wsf + 272;        // 256
  float* p2     = wsf + 528;        // 512
  float* q2     = wsf + 1040;       // 512
  float* logits = wsf + 2048;       // [2048][256] fp32
  ushort_t* usb = (ushort_t*)(wsf + 526400);
  ushort_t* A2  = usb;              // [2048][1024] bf16: [xt | h0]
  ushort_t* ABF = usb + 2097152;    // [2048][512]  bf16 attn_applied
  ushort_t* WTA = usb + 3145728;    // [256][512]
  ushort_t* WTC = usb + 3276800;    // [512][512]
  ushort_t* WTG = usb + 3538944;    // [2048][1024]

  kTiny<<<37, 256, 0, stream>>>(emb_W, emb_b, attn_W, WTA, stats, p, q);
  kLogits<<<dim3(16, 4), 256, 0, stream>>>(hidden, WTA, x, stats, p, q,
                                           attn_b, logits);
  kStreamMega<<<3152, 256, 0, stream>>>(hidden, Wih, Whh, comb_W, emb_W, emb_b,
                                        out_b, logits, enc, A2, WTG, WTC,
                                        p2, q2, out0, out_attn, ABF);
  kComb<<<dim3(16, 8), 256, 0, stream>>>(ABF, WTC, x, stats, p2, q2, comb_b, A2);
  kGRU<<<dim3(16, 32), 256, 0, stream>>>(A2, WTG, bih, bhh, hidden, out_W,
                                         out_h, out0);
}